// Round 9
// baseline (5907.983 us; speedup 1.0000x reference)
//
#include <hip/hip_runtime.h>
#include <hip/hip_bf16.h>

#define NLOW  8000
#define NHIGH 50000
#define NL25  200000
#define ELL   32000
#define ELH   1250000
#define EHH   800000

// int width-aware read (int32 vs int64 little-endian low word)
__device__ __forceinline__ int geti(const int* a, long long i, int i64flag) {
  return i64flag ? a[2 * i] : a[i];
}

// ---------------- int dtype probes ----------------
__global__ void k_probe_i(const int* in, int n, int* cnt) {
  int i = blockIdx.x * 256 + threadIdx.x;
  if (i >= n || !(i & 1)) return;
  if (in[i] != 0) atomicAdd(cnt, 1);
}
__global__ void k_decide_i(int* iflags, const int* cnt) {
  int t = threadIdx.x;
  if (t < 4) iflags[t] = (cnt[t] == 0) ? 1 : 0;  // all-zero odd words -> int64
}

// ---------------- diagnostics ----------------
__global__ void k_chk(const float* __restrict__ b, long long n, int bit,
                      int* __restrict__ diag) {
  long long i = (long long)blockIdx.x * 256 + threadIdx.x;
  if (i >= n) return;
  if (!(fabsf(b[i]) <= 1e30f)) atomicOr(diag, 1 << bit);
}
__global__ void k_chk_csr(const int* __restrict__ rp, const int* __restrict__ col,
                          int N, int E, int maxcol, int bit, int* __restrict__ diag) {
  int i = blockIdx.x * 256 + threadIdx.x;
  if (i < N) {
    int a = rp[i], b = rp[i + 1];
    if (a < 0 || b < a || b > E) atomicOr(diag, 1 << bit);
  }
  if (i < E) {
    int c = col[i];
    if (c < 0 || c >= maxcol) atomicOr(diag, 1 << bit);
  }
  if (i == 0 && rp[N] != E) atomicOr(diag, 1 << bit);
}
// Output is FLOAT32 (reference returns f32; harness maps output dtype from ref).
__global__ void k_out(const float* __restrict__ res, const int* __restrict__ diag,
                      float* __restrict__ o, int n) {
  int i = blockIdx.x * 256 + threadIdx.x;
  if (i >= n) return;
  int dg = *diag;
  float v = res[i];
  if (dg != 0) v = 1000.0f * (float)__ffs(dg);
  o[i] = v;
}
__global__ void k_fill_out(float* __restrict__ o, int n, float v) {
  int i = blockIdx.x * 256 + threadIdx.x;
  if (i < n) o[i] = v;
}

// ---------------- Stage 1: fused GCN (all f32) ----------------
__global__ void k_init_deg(float* __restrict__ deg) {
  int i = blockIdx.x * 256 + threadIdx.x;
  if (i < NLOW) deg[i] = 1.0f;
}
__global__ void k_gcn_deg(const int* __restrict__ ei, const int* __restrict__ iflags,
                          float* __restrict__ deg) {
  int e = blockIdx.x * 256 + threadIdx.x;
  if (e >= ELL) return;
  int d = geti(ei, ELL + e, iflags[0]);
  if (d >= 0 && d < NLOW) atomicAdd(&deg[d], 1.0f);
}
__global__ void k_xa_init(const float* __restrict__ x, const float* __restrict__ deg,
                          float* __restrict__ xa) {
  int i = blockIdx.x * 256 + threadIdx.x;
  if (i >= NLOW * 125) return;
  xa[i] = x[i] / deg[i / 125];
}
__global__ void k_xa_edge(const float* __restrict__ x, const int* __restrict__ ei,
                          const int* __restrict__ iflags, const float* __restrict__ deg,
                          float* __restrict__ xa) {
  int gid = blockIdx.x * 256 + threadIdx.x;
  if (gid >= ELL * 125) return;
  int e = gid / 125, k = gid - e * 125;
  int f = iflags[0];
  int s = geti(ei, e, f), d = geti(ei, ELL + e, f);
  if (s < 0 || s >= NLOW || d < 0 || d >= NLOW) return;
  float nrm = rsqrtf(deg[s]) * rsqrtf(deg[d]);
  atomicAdd(&xa[d * 125 + k], nrm * x[s * 125 + k]);
}
// M[vk, sp*100+j] = sum_c W[v,k,c*25+sp] * Wl[v*25+c, j]
__global__ void k_prep_M(const float* __restrict__ W, const float* __restrict__ Wl,
                         float* __restrict__ M) {
  int gid = blockIdx.x * 256 + threadIdx.x;
  if (gid >= 125 * 2500) return;
  int vk = gid / 2500, r = gid - vk * 2500, sp = r / 100, j = r - sp * 100;
  int v = vk / 25;
  float acc = 0.f;
#pragma unroll
  for (int c = 0; c < 25; c++)
    acc = fmaf(W[vk * 625 + c * 25 + sp], Wl[(v * 25 + c) * 100 + j], acc);
  M[gid] = acc;
}
__global__ void k_prep_b2(const float* __restrict__ b, const float* __restrict__ Wl,
                          const float* __restrict__ bl, float* __restrict__ b2) {
  int gid = blockIdx.x * 256 + threadIdx.x;
  if (gid >= 2500) return;
  int sp = gid / 100, j = gid - sp * 100;
  float acc = bl[j];
  for (int v = 0; v < 5; v++)
#pragma unroll
    for (int c = 0; c < 25; c++)
      acc = fmaf(b[v * 625 + c * 25 + sp], Wl[(v * 25 + c) * 100 + j], acc);
  b2[gid] = acc;
}
// half-width hl: channels [50p, 50p+50) of the 100, stored f32
__global__ void k_hlT50(const float* __restrict__ xa, const float* __restrict__ M,
                        const float* __restrict__ b2v, int pass,
                        float* __restrict__ out) {
  long long gid = (long long)blockIdx.x * 256 + threadIdx.x;
  if (gid >= (long long)NLOW * 1250) return;
  int n = (int)(gid / 1250);
  int r = (int)(gid - (long long)n * 1250);
  int sp = r / 50, jj = r - sp * 50;
  int j = 50 * pass + jj;
  const float* xr = xa + n * 125;
  const float* mr = M + sp * 100 + j;
  float acc = b2v[sp * 100 + j];
#pragma unroll 5
  for (int vk = 0; vk < 125; vk++) acc = fmaf(xr[vk], mr[vk * 2500], acc);
  out[gid] = acc;  // gid == (n*25+sp)*50 + jj
}

// ---------------- CSR build ----------------
__global__ void k_hist(const int* __restrict__ base, long long off, int E,
                       const int* __restrict__ iflags, int idx, int* __restrict__ cnt) {
  int e = blockIdx.x * 256 + threadIdx.x;
  if (e >= E) return;
  int d = geti(base, off + e, iflags[idx]);
  if (d >= 0 && d < NHIGH) atomicAdd(&cnt[d], 1);
}
__global__ void k_scan1(const int* __restrict__ cnt, int* __restrict__ rp,
                        int* __restrict__ part, int N) {
  __shared__ int sh[256];
  int i = blockIdx.x * 256 + threadIdx.x;
  int v = (i < N) ? cnt[i] : 0;
  sh[threadIdx.x] = v;
  __syncthreads();
  for (int off = 1; off < 256; off <<= 1) {
    int t = (threadIdx.x >= off) ? sh[threadIdx.x - off] : 0;
    __syncthreads();
    sh[threadIdx.x] += t;
    __syncthreads();
  }
  if (i < N) rp[i] = sh[threadIdx.x] - v;
  if (threadIdx.x == 255) part[blockIdx.x] = sh[255];
}
__global__ void k_scan2(int* __restrict__ part, int nb) {
  __shared__ int sh[256];
  int v = (threadIdx.x < nb) ? part[threadIdx.x] : 0;
  sh[threadIdx.x] = v;
  __syncthreads();
  for (int off = 1; off < 256; off <<= 1) {
    int t = (threadIdx.x >= off) ? sh[threadIdx.x - off] : 0;
    __syncthreads();
    sh[threadIdx.x] += t;
    __syncthreads();
  }
  if (threadIdx.x < nb) part[threadIdx.x] = sh[threadIdx.x] - v;
}
__global__ void k_scan3(int* __restrict__ rp, const int* __restrict__ part, int N, int E) {
  int i = blockIdx.x * 256 + threadIdx.x;
  if (i < N) rp[i] += part[i / 256];
  if (i == 0) rp[N] = E;
}
__global__ void k_csr_scatter(const int* __restrict__ sb, long long soff, int sidx,
                              const int* __restrict__ db, long long doff, int didx,
                              const int* __restrict__ iflags, const int* __restrict__ rp,
                              int* __restrict__ fil, int* __restrict__ col, int E) {
  int e = blockIdx.x * 256 + threadIdx.x;
  if (e >= E) return;
  int d = geti(db, doff + e, iflags[didx]);
  if (d < 0 || d >= NHIGH) return;
  int pos = rp[d] + atomicAdd(&fil[d], 1);
  if (pos >= 0 && pos < E) col[pos] = geti(sb, soff + e, iflags[sidx]);
}

// ---------------- Stage 2: bipartite GATv2, 2 heads per pass ----------------
__global__ void k_gat_th2(const float* __restrict__ hl50, const float* __restrict__ z,
                          const float* __restrict__ wr, const float* __restrict__ br,
                          const float* __restrict__ att, const int* __restrict__ rp,
                          const int* __restrict__ col, int pass,
                          float* __restrict__ acc25) {
  __shared__ float slog[1024];
  __shared__ float shr[50], satt[50], sden[2], sacc[50];
  int d = blockIdx.x, lane = threadIdx.x;
  int beg = rp[d];
  int deg = rp[d + 1] - beg;
  if (beg < 0) beg = 0;
  if (deg < 0) deg = 0;
  if (deg > 512) deg = 512;
  if (beg + deg > ELH) deg = (ELH - beg > 0) ? (ELH - beg) : 0;
  float zd = z[d];
  if (lane < 50) {
    int j = 50 * pass + lane;
    shr[lane] = fmaf(zd, wr[j], br[j]);
    satt[lane] = att[j];
  }
  __syncthreads();
  for (int i = lane; i < deg; i += 64) {
    int s = col[beg + i];
    if (s < 0 || s >= NL25) s = 0;
    const float* row = hl50 + (size_t)s * 50;
#pragma unroll
    for (int hh = 0; hh < 2; hh++) {
      float a = 0.f;
#pragma unroll
      for (int c = 0; c < 25; c++) {
        float e = row[hh * 25 + c] + shr[hh * 25 + c];
        e = (e > 0.f) ? e : 0.2f * e;
        a = fmaf(e, satt[hh * 25 + c], a);
      }
      slog[i * 2 + hh] = a;
    }
  }
  __syncthreads();
  if (lane < 2) {
    float m = -3.0e38f;
    for (int i = 0; i < deg; i++) m = fmaxf(m, slog[i * 2 + lane]);
    float den = 0.f;
    for (int i = 0; i < deg; i++) {
      float a = expf(slog[i * 2 + lane] - m);
      slog[i * 2 + lane] = a;
      den += a;
    }
    sden[lane] = fmaxf(den, 1e-16f);
  }
  __syncthreads();
  if (lane < 50) {
    int hh = lane / 25;
    float a = 0.f;
    for (int i = 0; i < deg; i++) {
      int s = col[beg + i];
      if (s < 0 || s >= NL25) s = 0;
      a = fmaf(slog[i * 2 + hh], hl50[(size_t)s * 50 + lane], a);
    }
    sacc[lane] = a / sden[hh];
  }
  __syncthreads();
  if (lane < 25) {
    float contrib = sacc[lane] + sacc[25 + lane];
    if (pass == 0) acc25[d * 25 + lane] = contrib;
    else           acc25[d * 25 + lane] += contrib;
  }
}
__global__ void k_th_fin(const float* __restrict__ acc25, const int* __restrict__ rp,
                         const float* __restrict__ bias, const float* __restrict__ z,
                         float* __restrict__ x26) {
  int gid = blockIdx.x * 256 + threadIdx.x;
  int node = gid / 26, j = gid - node * 26;
  if (node >= NHIGH) return;
  if (j == 0) {
    x26[node * 26] = z[node];
  } else {
    int dg = rp[node + 1] - rp[node];
    if (dg < 1) dg = 1;
    x26[node * 26 + j] = acc25[node * 25 + j - 1] / (4.0f * (float)dg) + bias[j - 1];
  }
}

// ---------------- high-res GATv2 (gather, one block per node) ----------------
template <int H, bool RELU>
__global__ void k_gat_hh(const float* __restrict__ hl, const float* __restrict__ hr,
                         const float* __restrict__ att, const float* __restrict__ bias,
                         const int* __restrict__ rp, const int* __restrict__ col,
                         float* __restrict__ out) {
  const int F = H * 64;
  __shared__ float slog[260 * H];
  __shared__ float shr[F];
  __shared__ float satt[F];
  __shared__ float sden[H];
  int d = blockIdx.x, lane = threadIdx.x;
  int beg = rp[d];
  int deg = rp[d + 1] - beg;
  if (beg < 0) beg = 0;
  if (deg < 0) deg = 0;
  if (deg > 258) deg = 258;
  if (beg + deg > EHH) deg = (EHH - beg > 0) ? (EHH - beg) : 0;
  int tot = deg + 1;  // + self loop
  for (int j = lane; j < F; j += 64) {
    shr[j] = hr[(size_t)d * F + j];
    satt[j] = att[j];
  }
  __syncthreads();
  for (int i = lane; i < tot; i += 64) {
    int s = (i < deg) ? col[beg + i] : d;
    if (s < 0 || s >= NHIGH) s = 0;
    const float* row = hl + (size_t)s * F;
#pragma unroll
    for (int h = 0; h < H; h++) {
      float acc = 0.f;
#pragma unroll 8
      for (int c = 0; c < 64; c++) {
        float e = row[h * 64 + c] + shr[h * 64 + c];
        e = (e > 0.f) ? e : 0.2f * e;
        acc = fmaf(e, satt[h * 64 + c], acc);
      }
      slog[i * H + h] = acc;
    }
  }
  __syncthreads();
  if (lane < H) {
    float m = -3.0e38f;
    for (int i = 0; i < tot; i++) m = fmaxf(m, slog[i * H + lane]);
    float den = 0.f;
    for (int i = 0; i < tot; i++) {
      float a = expf(slog[i * H + lane] - m);
      slog[i * H + lane] = a;
      den += a;
    }
    sden[lane] = fmaxf(den, 1e-16f) * (float)tot;  // softmax den * mean count
  }
  __syncthreads();
  int c = lane;
  float acc[H];
#pragma unroll
  for (int h = 0; h < H; h++) acc[h] = 0.f;
  for (int i = 0; i < tot; i++) {
    int s = (i < deg) ? col[beg + i] : d;
    if (s < 0 || s >= NHIGH) s = 0;
#pragma unroll
    for (int h = 0; h < H; h++)
      acc[h] += slog[i * H + h] * hl[(size_t)s * F + h * 64 + c];
  }
#pragma unroll
  for (int h = 0; h < H; h++) {
    float v = acc[h] / sden[h] + bias[h * 64 + c];
    if (RELU) v = fmaxf(v, 0.f);
    out[(size_t)d * F + h * 64 + c] = v;
  }
}

// ---------------- BatchNorm stats: two-pass (mean, then E[(x-mu)^2]) ----------------
__global__ void k_bn_stats(const float* __restrict__ x, int n, int C,
                           float* __restrict__ mu, float* __restrict__ var) {
  int c = blockIdx.x;
  __shared__ float ss[256];
  __shared__ float smean;
  float s = 0.f;
  for (int i = threadIdx.x; i < n; i += 256) s += x[(size_t)i * C + c];
  ss[threadIdx.x] = s;
  __syncthreads();
  for (int off = 128; off > 0; off >>= 1) {
    if (threadIdx.x < off) ss[threadIdx.x] += ss[threadIdx.x + off];
    __syncthreads();
  }
  if (threadIdx.x == 0) smean = ss[0] / n;
  __syncthreads();
  float m = smean;
  float s2 = 0.f;
  for (int i = threadIdx.x; i < n; i += 256) {
    float dv = x[(size_t)i * C + c] - m;
    s2 = fmaf(dv, dv, s2);
  }
  ss[threadIdx.x] = s2;
  __syncthreads();
  for (int off = 128; off > 0; off >>= 1) {
    if (threadIdx.x < off) ss[threadIdx.x] += ss[threadIdx.x + off];
    __syncthreads();
  }
  if (threadIdx.x == 0) {
    mu[c] = m;
    var[c] = ss[0] / n;
  }
}

template <int CIN, int COUT, bool BRELU>
__global__ void k_linear_bn(const float* __restrict__ x, const float* __restrict__ mu,
                            const float* __restrict__ var, const float* __restrict__ g,
                            const float* __restrict__ bb, const float* __restrict__ W,
                            const float* __restrict__ b, float* __restrict__ y, int n) {
  long long gid = (long long)blockIdx.x * 256 + threadIdx.x;
  int node = (int)(gid / COUT);
  int j = (int)(gid - (long long)node * COUT);
  if (node >= n) return;
  const float* xr = x + (size_t)node * CIN;
  float acc = b[j];
#pragma unroll 4
  for (int k = 0; k < CIN; k++) {
    float xn = (xr[k] - mu[k]) * rsqrtf(var[k] + 1e-5f) * g[k] + bb[k];
    if (BRELU) xn = fmaxf(xn, 0.f);
    acc = fmaf(xn, W[k * COUT + j], acc);
  }
  y[(size_t)node * COUT + j] = acc;
}

template <int CIN, int COUT, bool RELU>
__global__ void k_linear(const float* __restrict__ x, const float* __restrict__ W,
                         const float* __restrict__ b, float* __restrict__ y, int n) {
  long long gid = (long long)blockIdx.x * 256 + threadIdx.x;
  int node = (int)(gid / COUT);
  int j = (int)(gid - (long long)node * COUT);
  if (node >= n) return;
  const float* xr = x + (size_t)node * CIN;
  float acc = b[j];
#pragma unroll 4
  for (int k = 0; k < CIN; k++) acc = fmaf(xr[k], W[k * COUT + j], acc);
  if (RELU) acc = fmaxf(acc, 0.f);
  y[(size_t)node * COUT + j] = acc;
}

extern "C" void kernel_launch(void* const* d_in, const int* in_sizes, int n_in,
                              void* d_out, int out_size, void* d_ws, size_t ws_size,
                              hipStream_t stream) {
  auto nb = [](long long t) { return dim3((unsigned)((t + 255) / 256)); };
  static const int FSZ[38] = {
      1000000, 50000, 78125, 3125, 12500, 100, 100, 100, 100, 25, 26, 26,
      3328, 128, 3328, 128, 128, 128, 512, 512, 49152, 384, 49152, 384, 384,
      384, 8192, 64, 8192, 64, 64, 64, 4096, 64, 2048, 32, 32, 1};
  static const int ISZ[4] = {64000, 1250000, 1250000, 1600000};
  if (n_in != 42) {
    k_fill_out<<<nb(out_size), 256, 0, stream>>>((float*)d_out, out_size, 500000.0f);
    return;
  }
  bool szok = true;
  for (int i = 0; i < 38; i++) szok &= (in_sizes[i] == FSZ[i]);
  for (int i = 0; i < 4; i++) szok &= (in_sizes[38 + i] == ISZ[i]);
  if (!szok) {
    k_fill_out<<<nb(out_size), 256, 0, stream>>>((float*)d_out, out_size, 600000.0f);
    return;
  }
  const size_t REQUIRED = 20118800ull * 4ull;  // 80.5 MB (guard verified untriggered)
  if (ws_size < REQUIRED) {
    hipMemsetAsync(d_out, 0, (size_t)out_size * 4, stream);
    return;
  }

  const float* w[38];
  for (int i = 0; i < 38; i++) w[i] = (const float*)d_in[i];  // f32 confirmed (r6)
  const int* ei_ll = (const int*)d_in[38];
  const int* s_l2h = (const int*)d_in[39];
  const int* d_l2h = (const int*)d_in[40];
  const int* ei_hh = (const int*)d_in[41];

  float* ws = (float*)d_ws;
  // Stage-3+ slots:
  float* S0 = ws;                       // [0, 6.4M)
  float* S1 = ws + 6400000;             // [6.4M, 12.8M)
  float* S2 = ws + 12800000;            // [12.8M, 19.2M)
  // Stage-1/2 aliases (all dead before the S-slot covering them is written):
  float* hl50  = ws;                    // [10,000,000] f32 half-hl
  float* acc25 = ws + 10000000;         // [1,250,000]
  int*  rpT  = (int*)(ws + 11300000);   // [50,001]
  int*  filT = (int*)(ws + 11360000);   // [50,000]
  int*  colT = (int*)(ws + 11450000);   // [1,250,000] -> 12.7M
  float* xa  = ws + 12800000;           // [1,000,000] -> 13.8M
  float* Mt  = ws + 13800000;           // [312,500]  -> 14,112,500
  float* b2  = ws + 14112500;           // [2,500]    -> 14,115,000
  float* x26 = ws + 14200000;           // [1,300,000] -> 15.5M (dead before S2 written)
  // Persistent:
  int*  rpH  = (int*)(ws + 19200000);   // [50,001]
  int*  filH = (int*)(ws + 19260000);   // [50,000]
  int*  colH = (int*)(ws + 19310000);   // [800,000] -> 20,110,000
  float* deg = ws + 20110000;           // [8,000]
  float* mu  = ws + 20118000;           // [128]
  float* var = ws + 20118128;           // [128]
  int*  part = (int*)(ws + 20118256);   // [512] -> 20,118,768
  int* iflags = (int*)(ws + 20118768);  // [4]
  int* badi   = (int*)(ws + 20118772);  // [4]
  int* diag   = (int*)(ws + 20118776);  // [1]

  hipMemsetAsync(iflags, 0, 9 * 4, stream);

  // ---- int width probes ----
  for (int g = 0; g < 4; g++)
    k_probe_i<<<nb(ISZ[g]), 256, 0, stream>>>((const int*)d_in[38 + g], ISZ[g], badi + g);
  k_decide_i<<<1, 64, 0, stream>>>(iflags, badi);

  // ---- CSR for both graphs ----
  auto build_csr = [&](const int* sb, long long so, int si, const int* db, long long dofs,
                       int di, int E, int* rp, int* fil, int* col) {
    hipMemsetAsync(fil, 0, NHIGH * 4, stream);
    k_hist<<<nb(E), 256, 0, stream>>>(db, dofs, E, iflags, di, fil);
    int nblk = (NHIGH + 255) / 256;
    k_scan1<<<nblk, 256, 0, stream>>>(fil, rp, part, NHIGH);
    k_scan2<<<1, 256, 0, stream>>>(part, nblk);
    k_scan3<<<nb(NHIGH), 256, 0, stream>>>(rp, part, NHIGH, E);
    hipMemsetAsync(fil, 0, NHIGH * 4, stream);
    k_csr_scatter<<<nb(E), 256, 0, stream>>>(sb, so, si, db, dofs, di, iflags, rp, fil,
                                             col, E);
  };
  build_csr(s_l2h, 0, 1, d_l2h, 0, 2, ELH, rpT, filT, colT);
  build_csr(ei_hh, 0, 3, ei_hh, EHH, 3, EHH, rpH, filH, colH);
  k_chk_csr<<<nb(ELH), 256, 0, stream>>>(rpT, colT, NHIGH, ELH, NL25, 0, diag);
  k_chk_csr<<<nb(EHH), 256, 0, stream>>>(rpH, colH, NHIGH, EHH, NHIGH, 1, diag);

  // ---- Stage 1: GCN fold ----
  k_init_deg<<<nb(NLOW), 256, 0, stream>>>(deg);
  k_gcn_deg<<<nb(ELL), 256, 0, stream>>>(ei_ll, iflags, deg);
  k_xa_init<<<nb(NLOW * 125), 256, 0, stream>>>(w[0], deg, xa);
  k_xa_edge<<<nb((long long)ELL * 125), 256, 0, stream>>>(w[0], ei_ll, iflags, deg, xa);
  k_chk<<<nb(1000000), 256, 0, stream>>>(xa, 1000000, 2, diag);
  k_prep_M<<<nb(125 * 2500), 256, 0, stream>>>(w[2], w[4], Mt);
  k_prep_b2<<<nb(2500), 256, 0, stream>>>(w[3], w[4], w[5], b2);
  k_chk<<<nb(312500), 256, 0, stream>>>(Mt, 312500, 3, diag);
  k_chk<<<nb(2500), 256, 0, stream>>>(b2, 2500, 3, diag);

  // ---- Stage 2: th GATv2, 2 head-passes, f32 throughout ----
  for (int p = 0; p < 2; p++) {
    k_hlT50<<<nb((long long)NLOW * 1250), 256, 0, stream>>>(xa, Mt, b2, p, hl50);
    k_chk<<<nb(10000000), 256, 0, stream>>>(hl50, 10000000, 4, diag);
    k_gat_th2<<<NHIGH, 64, 0, stream>>>(hl50, w[1], w[6], w[7], w[8], rpT, colT, p,
                                        acc25);
  }
  k_chk<<<nb(1250000), 256, 0, stream>>>(acc25, 1250000, 5, diag);
  k_th_fin<<<nb((long long)NHIGH * 26), 256, 0, stream>>>(acc25, rpT, w[9], w[1], x26);
  k_chk<<<nb(1300000), 256, 0, stream>>>(x26, 1300000, 6, diag);

  // ---- Stage 3: bn0 + g1 ----
  k_bn_stats<<<26, 256, 0, stream>>>(x26, NHIGH, 26, mu, var);
  k_linear_bn<26, 128, false><<<nb((long long)NHIGH * 128), 256, 0, stream>>>(
      x26, mu, var, w[10], w[11], w[12], w[13], S0, NHIGH);
  k_linear_bn<26, 128, false><<<nb((long long)NHIGH * 128), 256, 0, stream>>>(
      x26, mu, var, w[10], w[11], w[14], w[15], S1, NHIGH);
  k_chk<<<nb(6400000), 256, 0, stream>>>(S0, 6400000, 7, diag);
  k_chk<<<nb(6400000), 256, 0, stream>>>(S1, 6400000, 7, diag);
  k_gat_hh<2, false><<<NHIGH, 64, 0, stream>>>(S0, S1, w[16], w[17], rpH, colH, S2);
  k_chk<<<nb(6400000), 256, 0, stream>>>(S2, 6400000, 8, diag);

  // ---- Stage 4: 3x gm ----
  for (int i = 0; i < 3; i++) {
    k_bn_stats<<<128, 256, 0, stream>>>(S2, NHIGH, 128, mu, var);
    k_linear_bn<128, 128, true><<<nb((long long)NHIGH * 128), 256, 0, stream>>>(
        S2, mu, var, w[18] + i * 128, w[19] + i * 128, w[20] + i * 16384,
        w[21] + i * 128, S0, NHIGH);
    k_linear_bn<128, 128, true><<<nb((long long)NHIGH * 128), 256, 0, stream>>>(
        S2, mu, var, w[18] + i * 128, w[19] + i * 128, w[22] + i * 16384,
        w[23] + i * 128, S1, NHIGH);
    k_gat_hh<2, false><<<NHIGH, 64, 0, stream>>>(S0, S1, w[24] + i * 128,
                                                 w[25] + i * 128, rpH, colH, S2);
    k_chk<<<nb(6400000), 256, 0, stream>>>(S2, 6400000, 9 + i, diag);
  }

  // ---- Stage 5: g5 ----
  k_bn_stats<<<128, 256, 0, stream>>>(S2, NHIGH, 128, mu, var);
  k_linear_bn<128, 64, true><<<nb((long long)NHIGH * 64), 256, 0, stream>>>(
      S2, mu, var, w[18] + 384, w[19] + 384, w[26], w[27], S0, NHIGH);
  k_linear_bn<128, 64, true><<<nb((long long)NHIGH * 64), 256, 0, stream>>>(
      S2, mu, var, w[18] + 384, w[19] + 384, w[28], w[29], S1, NHIGH);
  k_chk<<<nb(3200000), 256, 0, stream>>>(S0, 3200000, 12, diag);
  k_chk<<<nb(3200000), 256, 0, stream>>>(S1, 3200000, 12, diag);
  k_gat_hh<1, true><<<NHIGH, 64, 0, stream>>>(S0, S1, w[30], w[31], rpH, colH, S2);
  k_chk<<<nb(3200000), 256, 0, stream>>>(S2, 3200000, 13, diag);

  // ---- Stage 6: MLP ----
  k_linear<64, 64, true><<<nb((long long)NHIGH * 64), 256, 0, stream>>>(
      S2, w[32], w[33], S0, NHIGH);
  k_linear<64, 32, true><<<nb((long long)NHIGH * 32), 256, 0, stream>>>(
      S0, w[34], w[35], S1, NHIGH);
  k_linear<32, 1, false><<<nb((long long)NHIGH), 256, 0, stream>>>(
      S1, w[36], w[37], S2, NHIGH);
  k_chk<<<nb(NHIGH), 256, 0, stream>>>(S2, NHIGH, 14, diag);

  k_out<<<nb(NHIGH), 256, 0, stream>>>(S2, diag, (float*)d_out, NHIGH);
}

// Round 10
// 4076.851 us; speedup vs baseline: 1.4492x; 1.4492x over previous
//
#include <hip/hip_runtime.h>

#define NLOW  8000
#define NHIGH 50000
#define NL25  200000
#define ELL   32000
#define ELH   1250000
#define EHH   800000

// int width-aware read (int32 vs int64 little-endian low word)
__device__ __forceinline__ int geti(const int* a, long long i, int i64flag) {
  return i64flag ? a[2 * i] : a[i];
}

// ---------------- int dtype probes ----------------
__global__ void k_probe_i(const int* in, int n, int* cnt) {
  int i = blockIdx.x * 256 + threadIdx.x;
  if (i >= n || !(i & 1)) return;
  if (in[i] != 0) atomicAdd(cnt, 1);
}
__global__ void k_decide_i(int* iflags, const int* cnt) {
  int t = threadIdx.x;
  if (t < 4) iflags[t] = (cnt[t] == 0) ? 1 : 0;  // all-zero odd words -> int64
}
__global__ void k_fill_out(float* __restrict__ o, int n, float v) {
  int i = blockIdx.x * 256 + threadIdx.x;
  if (i < n) o[i] = v;
}

// ---------------- Stage 1: fused GCN ----------------
__global__ void k_init_deg(float* __restrict__ deg) {
  int i = blockIdx.x * 256 + threadIdx.x;
  if (i < NLOW) deg[i] = 1.0f;
}
__global__ void k_gcn_deg(const int* __restrict__ ei, const int* __restrict__ iflags,
                          float* __restrict__ deg) {
  int e = blockIdx.x * 256 + threadIdx.x;
  if (e >= ELL) return;
  int d = geti(ei, ELL + e, iflags[0]);
  if (d >= 0 && d < NLOW) atomicAdd(&deg[d], 1.0f);
}
__global__ void k_xa_init(const float* __restrict__ x, const float* __restrict__ deg,
                          float* __restrict__ xa) {
  int i = blockIdx.x * 256 + threadIdx.x;
  if (i >= NLOW * 125) return;
  xa[i] = x[i] / deg[i / 125];
}
__global__ void k_xa_edge(const float* __restrict__ x, const int* __restrict__ ei,
                          const int* __restrict__ iflags, const float* __restrict__ deg,
                          float* __restrict__ xa) {
  int gid = blockIdx.x * 256 + threadIdx.x;
  if (gid >= ELL * 125) return;
  int e = gid / 125, k = gid - e * 125;
  int f = iflags[0];
  int s = geti(ei, e, f), d = geti(ei, ELL + e, f);
  if (s < 0 || s >= NLOW || d < 0 || d >= NLOW) return;
  float nrm = rsqrtf(deg[s]) * rsqrtf(deg[d]);
  atomicAdd(&xa[d * 125 + k], nrm * x[s * 125 + k]);
}
// M[vk, sp*100+j] = sum_c W[v,k,c*25+sp] * Wl[v*25+c, j]
__global__ void k_prep_M(const float* __restrict__ W, const float* __restrict__ Wl,
                         float* __restrict__ M) {
  int gid = blockIdx.x * 256 + threadIdx.x;
  if (gid >= 125 * 2500) return;
  int vk = gid / 2500, r = gid - vk * 2500, sp = r / 100, j = r - sp * 100;
  int v = vk / 25;
  float acc = 0.f;
#pragma unroll
  for (int c = 0; c < 25; c++)
    acc = fmaf(W[vk * 625 + c * 25 + sp], Wl[(v * 25 + c) * 100 + j], acc);
  M[gid] = acc;
}
__global__ void k_prep_b2(const float* __restrict__ b, const float* __restrict__ Wl,
                          const float* __restrict__ bl, float* __restrict__ b2) {
  int gid = blockIdx.x * 256 + threadIdx.x;
  if (gid >= 2500) return;
  int sp = gid / 100, j = gid - sp * 100;
  float acc = bl[j];
  for (int v = 0; v < 5; v++)
#pragma unroll
    for (int c = 0; c < 25; c++)
      acc = fmaf(b[v * 625 + c * 25 + sp], Wl[(v * 25 + c) * 100 + j], acc);
  b2[gid] = acc;
}

// Tiled GEMM: out[n, b] = sum_k xa[n,k]*M[k, cm(b)] + b2[cm(b)], b in [0,1250)
// cm(b) = (b/50)*100 + 50*pass + b%50.  Grid (125 row-tiles, 20 col-tiles), 256 thr.
__global__ void k_hlT_gemm(const float* __restrict__ A, const float* __restrict__ M,
                           const float* __restrict__ b2v, int pass,
                           float* __restrict__ out) {
  __shared__ float As[32 * 65];  // [k][row], pad 65
  __shared__ float Bs[32 * 68];  // [k][col], pad 68 (16B-aligned rows)
  int t = threadIdx.x;
  int tx = t & 15, ty = t >> 4;
  int row0 = blockIdx.x * 64, col0 = blockIdx.y * 64;
  float acc[4][4];
#pragma unroll
  for (int i = 0; i < 4; i++)
#pragma unroll
    for (int j = 0; j < 4; j++) acc[i][j] = 0.f;
  for (int k0 = 0; k0 < 125; k0 += 32) {
    int kw = 125 - k0; if (kw > 32) kw = 32;
    for (int l = t; l < 64 * 32; l += 256) {
      int r = l >> 5, kk = l & 31;
      As[kk * 65 + r] = (kk < kw) ? A[(size_t)(row0 + r) * 125 + k0 + kk] : 0.f;
    }
    for (int l = t; l < 32 * 64; l += 256) {
      int kk = l >> 6, bb = l & 63;
      int b = col0 + bb;
      float v = 0.f;
      if (kk < kw && b < 1250) {
        int cm = (b / 50) * 100 + 50 * pass + (b % 50);
        v = M[(size_t)(k0 + kk) * 2500 + cm];
      }
      Bs[kk * 68 + bb] = v;
    }
    __syncthreads();
#pragma unroll 8
    for (int kk = 0; kk < 32; kk++) {
      float a0 = As[kk * 65 + ty * 4 + 0];
      float a1 = As[kk * 65 + ty * 4 + 1];
      float a2 = As[kk * 65 + ty * 4 + 2];
      float a3 = As[kk * 65 + ty * 4 + 3];
      float b0 = Bs[kk * 68 + tx * 4 + 0];
      float b1 = Bs[kk * 68 + tx * 4 + 1];
      float b2x = Bs[kk * 68 + tx * 4 + 2];
      float b3 = Bs[kk * 68 + tx * 4 + 3];
      acc[0][0] = fmaf(a0, b0, acc[0][0]); acc[0][1] = fmaf(a0, b1, acc[0][1]);
      acc[0][2] = fmaf(a0, b2x, acc[0][2]); acc[0][3] = fmaf(a0, b3, acc[0][3]);
      acc[1][0] = fmaf(a1, b0, acc[1][0]); acc[1][1] = fmaf(a1, b1, acc[1][1]);
      acc[1][2] = fmaf(a1, b2x, acc[1][2]); acc[1][3] = fmaf(a1, b3, acc[1][3]);
      acc[2][0] = fmaf(a2, b0, acc[2][0]); acc[2][1] = fmaf(a2, b1, acc[2][1]);
      acc[2][2] = fmaf(a2, b2x, acc[2][2]); acc[2][3] = fmaf(a2, b3, acc[2][3]);
      acc[3][0] = fmaf(a3, b0, acc[3][0]); acc[3][1] = fmaf(a3, b1, acc[3][1]);
      acc[3][2] = fmaf(a3, b2x, acc[3][2]); acc[3][3] = fmaf(a3, b3, acc[3][3]);
    }
    __syncthreads();
  }
#pragma unroll
  for (int i = 0; i < 4; i++) {
    int r = row0 + ty * 4 + i;
#pragma unroll
    for (int j = 0; j < 4; j++) {
      int b = col0 + tx * 4 + j;
      if (b < 1250) {
        int cm = (b / 50) * 100 + 50 * pass + (b % 50);
        out[(size_t)r * 1250 + b] = acc[i][j] + b2v[cm];
      }
    }
  }
}

// ---------------- CSR build ----------------
__global__ void k_hist(const int* __restrict__ base, long long off, int E,
                       const int* __restrict__ iflags, int idx, int* __restrict__ cnt) {
  int e = blockIdx.x * 256 + threadIdx.x;
  if (e >= E) return;
  int d = geti(base, off + e, iflags[idx]);
  if (d >= 0 && d < NHIGH) atomicAdd(&cnt[d], 1);
}
__global__ void k_scan1(const int* __restrict__ cnt, int* __restrict__ rp,
                        int* __restrict__ part, int N) {
  __shared__ int sh[256];
  int i = blockIdx.x * 256 + threadIdx.x;
  int v = (i < N) ? cnt[i] : 0;
  sh[threadIdx.x] = v;
  __syncthreads();
  for (int off = 1; off < 256; off <<= 1) {
    int t = (threadIdx.x >= off) ? sh[threadIdx.x - off] : 0;
    __syncthreads();
    sh[threadIdx.x] += t;
    __syncthreads();
  }
  if (i < N) rp[i] = sh[threadIdx.x] - v;
  if (threadIdx.x == 255) part[blockIdx.x] = sh[255];
}
__global__ void k_scan2(int* __restrict__ part, int nb) {
  __shared__ int sh[256];
  int v = (threadIdx.x < nb) ? part[threadIdx.x] : 0;
  sh[threadIdx.x] = v;
  __syncthreads();
  for (int off = 1; off < 256; off <<= 1) {
    int t = (threadIdx.x >= off) ? sh[threadIdx.x - off] : 0;
    __syncthreads();
    sh[threadIdx.x] += t;
    __syncthreads();
  }
  if (threadIdx.x < nb) part[threadIdx.x] = sh[threadIdx.x] - v;
}
__global__ void k_scan3(int* __restrict__ rp, const int* __restrict__ part, int N, int E) {
  int i = blockIdx.x * 256 + threadIdx.x;
  if (i < N) rp[i] += part[i / 256];
  if (i == 0) rp[N] = E;
}
__global__ void k_csr_scatter(const int* __restrict__ sb, long long soff, int sidx,
                              const int* __restrict__ db, long long doff, int didx,
                              const int* __restrict__ iflags, const int* __restrict__ rp,
                              int* __restrict__ fil, int* __restrict__ col, int E) {
  int e = blockIdx.x * 256 + threadIdx.x;
  if (e >= E) return;
  int d = geti(db, doff + e, iflags[didx]);
  if (d < 0 || d >= NHIGH) return;
  int pos = rp[d] + atomicAdd(&fil[d], 1);
  if (pos >= 0 && pos < E) col[pos] = geti(sb, soff + e, iflags[sidx]);
}

// ---------------- Stage 2: bipartite GATv2 (shfl logits) ----------------
__global__ void k_gat_th2(const float* __restrict__ hl50, const float* __restrict__ z,
                          const float* __restrict__ wr, const float* __restrict__ br,
                          const float* __restrict__ att, const int* __restrict__ rp,
                          const int* __restrict__ col, int pass,
                          float* __restrict__ acc25) {
  __shared__ float slog[1024];
  __shared__ float shr[50], satt[50], sden[2], sacc[50];
  int d = blockIdx.x, lane = threadIdx.x;
  int beg = rp[d];
  int deg = rp[d + 1] - beg;
  if (beg < 0) beg = 0;
  if (deg < 0) deg = 0;
  if (deg > 512) deg = 512;
  if (beg + deg > ELH) deg = (ELH - beg > 0) ? (ELH - beg) : 0;
  float zd = z[d];
  if (lane < 50) {
    int j = 50 * pass + lane;
    shr[lane] = fmaf(zd, wr[j], br[j]);
    satt[lane] = att[j];
  }
  __syncthreads();
  int g = lane >> 5, cc = lane & 31;  // head-half, channel within head
  for (int i = 0; i < deg; i++) {
    int s = col[beg + i];
    if (s < 0 || s >= NL25) s = 0;
    float p = 0.f;
    if (cc < 25) {
      float e = hl50[(size_t)s * 50 + g * 25 + cc] + shr[g * 25 + cc];
      e = (e > 0.f) ? e : 0.2f * e;
      p = e * satt[g * 25 + cc];
    }
#pragma unroll
    for (int off = 16; off > 0; off >>= 1) p += __shfl_xor(p, off, 64);
    if (cc == 0) slog[i * 2 + g] = p;
  }
  __syncthreads();
  if (lane < 2) {
    float m = -3.0e38f;
    for (int i = 0; i < deg; i++) m = fmaxf(m, slog[i * 2 + lane]);
    float den = 0.f;
    for (int i = 0; i < deg; i++) {
      float a = expf(slog[i * 2 + lane] - m);
      slog[i * 2 + lane] = a;
      den += a;
    }
    sden[lane] = fmaxf(den, 1e-16f);
  }
  __syncthreads();
  if (lane < 50) {
    int hh = lane / 25;
    float a = 0.f;
    for (int i = 0; i < deg; i++) {
      int s = col[beg + i];
      if (s < 0 || s >= NL25) s = 0;
      a = fmaf(slog[i * 2 + hh], hl50[(size_t)s * 50 + lane], a);
    }
    sacc[lane] = a / sden[hh];
  }
  __syncthreads();
  if (lane < 25) {
    float contrib = sacc[lane] + sacc[25 + lane];
    if (pass == 0) acc25[d * 25 + lane] = contrib;
    else           acc25[d * 25 + lane] += contrib;
  }
}
__global__ void k_th_fin(const float* __restrict__ acc25, const int* __restrict__ rp,
                         const float* __restrict__ bias, const float* __restrict__ z,
                         float* __restrict__ x26) {
  int gid = blockIdx.x * 256 + threadIdx.x;
  int node = gid / 26, j = gid - node * 26;
  if (node >= NHIGH) return;
  if (j == 0) {
    x26[node * 26] = z[node];
  } else {
    int dg = rp[node + 1] - rp[node];
    if (dg < 1) dg = 1;
    x26[node * 26 + j] = acc25[node * 25 + j - 1] / (4.0f * (float)dg) + bias[j - 1];
  }
}

// ---------------- high-res GATv2 (coalesced logits via shfl) ----------------
template <int H, bool RELU>
__global__ void k_gat_hh(const float* __restrict__ hl, const float* __restrict__ hr,
                         const float* __restrict__ att, const float* __restrict__ bias,
                         const int* __restrict__ rp, const int* __restrict__ col,
                         float* __restrict__ out) {
  const int F = H * 64;
  __shared__ float slog[260 * H];
  __shared__ float shr[F];
  __shared__ float satt[F];
  __shared__ float sden[H];
  int d = blockIdx.x, lane = threadIdx.x;
  int beg = rp[d];
  int deg = rp[d + 1] - beg;
  if (beg < 0) beg = 0;
  if (deg < 0) deg = 0;
  if (deg > 258) deg = 258;
  if (beg + deg > EHH) deg = (EHH - beg > 0) ? (EHH - beg) : 0;
  int tot = deg + 1;  // + self loop
  for (int j = lane; j < F; j += 64) {
    shr[j] = hr[(size_t)d * F + j];
    satt[j] = att[j];
  }
  __syncthreads();
  // logit phase: coalesced row loads, cross-lane reduce
  for (int i = 0; i < tot; i++) {
    int s = (i < deg) ? col[beg + i] : d;
    if (s < 0 || s >= NHIGH) s = 0;
    const float* row = hl + (size_t)s * F;
    float e0 = row[lane] + shr[lane];
    e0 = (e0 > 0.f) ? e0 : 0.2f * e0;
    float p0 = e0 * satt[lane];
    if (H == 2) {
      float e1 = row[64 + lane] + shr[64 + lane];
      e1 = (e1 > 0.f) ? e1 : 0.2f * e1;
      float p1 = e1 * satt[64 + lane];
#pragma unroll
      for (int off = 32; off > 0; off >>= 1) {
        p0 += __shfl_xor(p0, off, 64);
        p1 += __shfl_xor(p1, off, 64);
      }
      if (lane == 0) { slog[i * 2] = p0; slog[i * 2 + 1] = p1; }
    } else {
#pragma unroll
      for (int off = 32; off > 0; off >>= 1) p0 += __shfl_xor(p0, off, 64);
      if (lane == 0) slog[i] = p0;
    }
  }
  __syncthreads();
  if (lane < H) {
    float m = -3.0e38f;
    for (int i = 0; i < tot; i++) m = fmaxf(m, slog[i * H + lane]);
    float den = 0.f;
    for (int i = 0; i < tot; i++) {
      float a = expf(slog[i * H + lane] - m);
      slog[i * H + lane] = a;
      den += a;
    }
    sden[lane] = fmaxf(den, 1e-16f) * (float)tot;  // softmax den * mean count
  }
  __syncthreads();
  int c = lane;
  float acc[H];
#pragma unroll
  for (int h = 0; h < H; h++) acc[h] = 0.f;
  for (int i = 0; i < tot; i++) {
    int s = (i < deg) ? col[beg + i] : d;
    if (s < 0 || s >= NHIGH) s = 0;
#pragma unroll
    for (int h = 0; h < H; h++)
      acc[h] += slog[i * H + h] * hl[(size_t)s * F + h * 64 + c];
  }
#pragma unroll
  for (int h = 0; h < H; h++) {
    float v = acc[h] / sden[h] + bias[h * 64 + c];
    if (RELU) v = fmaxf(v, 0.f);
    out[(size_t)d * F + h * 64 + c] = v;
  }
}

// ---------------- BatchNorm: parallel partials + f64 finalize -> scale/shift ----------------
// grid = 100 chunks of 500 rows; block 256; C*(256/C) threads active; fully coalesced.
__global__ void k_bn_part(const float* __restrict__ x, int C, int tpc,
                          float* __restrict__ ps, float* __restrict__ ps2) {
  int gch = blockIdx.x, t = threadIdx.x;
  int c = t % C, sub = t / C;
  float s = 0.f, s2 = 0.f;
  if (sub < tpc) {
    for (int r = gch * 500 + sub; r < gch * 500 + 500; r += tpc) {
      float v = x[(size_t)r * C + c];
      s += v;
      s2 = fmaf(v, v, s2);
    }
  }
  __shared__ float ls[256], ls2[256];
  ls[t] = s; ls2[t] = s2;
  __syncthreads();
  if (t < C) {
    float a = 0.f, a2 = 0.f;
    for (int u = 0; u < tpc; u++) { a += ls[u * C + t]; a2 += ls2[u * C + t]; }
    ps[gch * C + t] = a;
    ps2[gch * C + t] = a2;
  }
}
__global__ void k_bn_fin(const float* __restrict__ ps, const float* __restrict__ ps2,
                         int C, float n, const float* __restrict__ g,
                         const float* __restrict__ b, float* __restrict__ sc,
                         float* __restrict__ sh) {
  int c = blockIdx.x, t = threadIdx.x;
  __shared__ double ds[128], ds2[128];
  double a = 0, a2 = 0;
  for (int q = t; q < 100; q += 128) { a += ps[q * C + c]; a2 += ps2[q * C + c]; }
  ds[t] = a; ds2[t] = a2;
  __syncthreads();
  for (int off = 64; off > 0; off >>= 1) {
    if (t < off) { ds[t] += ds[t + off]; ds2[t] += ds2[t + off]; }
    __syncthreads();
  }
  if (t == 0) {
    double m = ds[0] / n;
    double v = ds2[0] / n - m * m;
    if (v < 0) v = 0;
    float scale = g[c] * rsqrtf((float)v + 1e-5f);
    sc[c] = scale;
    sh[c] = b[c] - (float)m * scale;
  }
}

// y = [relu](x*sc+sh) @ W + b
template <int CIN, int COUT, bool BRELU>
__global__ void k_linear_bn(const float* __restrict__ x, const float* __restrict__ sc,
                            const float* __restrict__ sh, const float* __restrict__ W,
                            const float* __restrict__ b, float* __restrict__ y, int n) {
  long long gid = (long long)blockIdx.x * 256 + threadIdx.x;
  int node = (int)(gid / COUT);
  int j = (int)(gid - (long long)node * COUT);
  if (node >= n) return;
  const float* xr = x + (size_t)node * CIN;
  float acc = b[j];
#pragma unroll 4
  for (int k = 0; k < CIN; k++) {
    float xn = fmaf(xr[k], sc[k], sh[k]);
    if (BRELU) xn = fmaxf(xn, 0.f);
    acc = fmaf(xn, W[k * COUT + j], acc);
  }
  y[(size_t)node * COUT + j] = acc;
}

template <int CIN, int COUT, bool RELU>
__global__ void k_linear(const float* __restrict__ x, const float* __restrict__ W,
                         const float* __restrict__ b, float* __restrict__ y, int n) {
  long long gid = (long long)blockIdx.x * 256 + threadIdx.x;
  int node = (int)(gid / COUT);
  int j = (int)(gid - (long long)node * COUT);
  if (node >= n) return;
  const float* xr = x + (size_t)node * CIN;
  float acc = b[j];
#pragma unroll 4
  for (int k = 0; k < CIN; k++) acc = fmaf(xr[k], W[k * COUT + j], acc);
  if (RELU) acc = fmaxf(acc, 0.f);
  y[(size_t)node * COUT + j] = acc;
}

extern "C" void kernel_launch(void* const* d_in, const int* in_sizes, int n_in,
                              void* d_out, int out_size, void* d_ws, size_t ws_size,
                              hipStream_t stream) {
  auto nb = [](long long t) { return dim3((unsigned)((t + 255) / 256)); };
  static const int FSZ[38] = {
      1000000, 50000, 78125, 3125, 12500, 100, 100, 100, 100, 25, 26, 26,
      3328, 128, 3328, 128, 128, 128, 512, 512, 49152, 384, 49152, 384, 384,
      384, 8192, 64, 8192, 64, 64, 64, 4096, 64, 2048, 32, 32, 1};
  static const int ISZ[4] = {64000, 1250000, 1250000, 1600000};
  if (n_in != 42) {
    k_fill_out<<<nb(out_size), 256, 0, stream>>>((float*)d_out, out_size, 500000.0f);
    return;
  }
  bool szok = true;
  for (int i = 0; i < 38; i++) szok &= (in_sizes[i] == FSZ[i]);
  for (int i = 0; i < 4; i++) szok &= (in_sizes[38 + i] == ISZ[i]);
  if (!szok) {
    k_fill_out<<<nb(out_size), 256, 0, stream>>>((float*)d_out, out_size, 600000.0f);
    return;
  }
  const size_t REQUIRED = 20146000ull * 4ull;  // 80.6 MB (ws >= 83.8 MB verified r3)
  if (ws_size < REQUIRED) {
    hipMemsetAsync(d_out, 0, (size_t)out_size * 4, stream);
    return;
  }

  const float* w[38];
  for (int i = 0; i < 38; i++) w[i] = (const float*)d_in[i];  // f32 (verified r6/r9)
  const int* ei_ll = (const int*)d_in[38];
  const int* s_l2h = (const int*)d_in[39];
  const int* d_l2h = (const int*)d_in[40];
  const int* ei_hh = (const int*)d_in[41];

  float* ws = (float*)d_ws;
  float* S0 = ws;                       // [0, 6.4M)
  float* S1 = ws + 6400000;             // [6.4M, 12.8M)
  float* S2 = ws + 12800000;            // [12.8M, 19.2M)
  // Stage-1/2 aliases (disjoint lifetimes vs S-slots):
  float* hl50  = ws;                    // [10,000,000]
  float* acc25 = ws + 10000000;         // [1,250,000]
  int*  rpT  = (int*)(ws + 11300000);   // [50,001]
  int*  filT = (int*)(ws + 11360000);   // [50,000]
  int*  colT = (int*)(ws + 11450000);   // [1,250,000] -> 12.7M
  float* xa  = ws + 12800000;           // [1,000,000]
  float* Mt  = ws + 13800000;           // [312,500]
  float* b2  = ws + 14112500;           // [2,500]
  float* x26 = ws + 14200000;           // [1,300,000] (dead before S2 written)
  // Persistent:
  int*  rpH  = (int*)(ws + 19200000);   // [50,001]
  int*  filH = (int*)(ws + 19260000);   // [50,000]
  int*  colH = (int*)(ws + 19310000);   // [800,000] -> 20,110,000
  float* deg = ws + 20110000;           // [8,000]
  float* sc  = ws + 20118000;           // [128]
  float* sh  = ws + 20118128;           // [128]
  int*  part = (int*)(ws + 20118256);   // [512]
  int* iflags = (int*)(ws + 20118768);  // [4]
  int* badi   = (int*)(ws + 20118772);  // [4]
  float* ps   = ws + 20120000;          // [12,800]
  float* ps2  = ws + 20132800;          // [12,800] -> 20,145,600

  hipMemsetAsync(iflags, 0, 8 * 4, stream);

  // ---- int width probes ----
  for (int g = 0; g < 4; g++)
    k_probe_i<<<nb(ISZ[g]), 256, 0, stream>>>((const int*)d_in[38 + g], ISZ[g], badi + g);
  k_decide_i<<<1, 64, 0, stream>>>(iflags, badi);

  // ---- CSR for both graphs ----
  auto build_csr = [&](const int* sb, long long so, int si, const int* db, long long dofs,
                       int di, int E, int* rp, int* fil, int* col) {
    hipMemsetAsync(fil, 0, NHIGH * 4, stream);
    k_hist<<<nb(E), 256, 0, stream>>>(db, dofs, E, iflags, di, fil);
    int nblk = (NHIGH + 255) / 256;
    k_scan1<<<nblk, 256, 0, stream>>>(fil, rp, part, NHIGH);
    k_scan2<<<1, 256, 0, stream>>>(part, nblk);
    k_scan3<<<nb(NHIGH), 256, 0, stream>>>(rp, part, NHIGH, E);
    hipMemsetAsync(fil, 0, NHIGH * 4, stream);
    k_csr_scatter<<<nb(E), 256, 0, stream>>>(sb, so, si, db, dofs, di, iflags, rp, fil,
                                             col, E);
  };
  build_csr(s_l2h, 0, 1, d_l2h, 0, 2, ELH, rpT, filT, colT);
  build_csr(ei_hh, 0, 3, ei_hh, EHH, 3, EHH, rpH, filH, colH);

  // ---- Stage 1: GCN fold ----
  k_init_deg<<<nb(NLOW), 256, 0, stream>>>(deg);
  k_gcn_deg<<<nb(ELL), 256, 0, stream>>>(ei_ll, iflags, deg);
  k_xa_init<<<nb(NLOW * 125), 256, 0, stream>>>(w[0], deg, xa);
  k_xa_edge<<<nb((long long)ELL * 125), 256, 0, stream>>>(w[0], ei_ll, iflags, deg, xa);
  k_prep_M<<<nb(125 * 2500), 256, 0, stream>>>(w[2], w[4], Mt);
  k_prep_b2<<<nb(2500), 256, 0, stream>>>(w[3], w[4], w[5], b2);

  // ---- Stage 2: th GATv2, 2 head-passes ----
  for (int p = 0; p < 2; p++) {
    k_hlT_gemm<<<dim3(125, 20), 256, 0, stream>>>(xa, Mt, b2, p, hl50);
    k_gat_th2<<<NHIGH, 64, 0, stream>>>(hl50, w[1], w[6], w[7], w[8], rpT, colT, p,
                                        acc25);
  }
  k_th_fin<<<nb((long long)NHIGH * 26), 256, 0, stream>>>(acc25, rpT, w[9], w[1], x26);

  // ---- Stage 3: bn0 + g1 ----
  k_bn_part<<<100, 256, 0, stream>>>(x26, 26, 9, ps, ps2);
  k_bn_fin<<<26, 128, 0, stream>>>(ps, ps2, 26, (float)NHIGH, w[10], w[11], sc, sh);
  k_linear_bn<26, 128, false><<<nb((long long)NHIGH * 128), 256, 0, stream>>>(
      x26, sc, sh, w[12], w[13], S0, NHIGH);
  k_linear_bn<26, 128, false><<<nb((long long)NHIGH * 128), 256, 0, stream>>>(
      x26, sc, sh, w[14], w[15], S1, NHIGH);
  k_gat_hh<2, false><<<NHIGH, 64, 0, stream>>>(S0, S1, w[16], w[17], rpH, colH, S2);

  // ---- Stage 4: 3x gm ----
  for (int i = 0; i < 3; i++) {
    k_bn_part<<<100, 256, 0, stream>>>(S2, 128, 2, ps, ps2);
    k_bn_fin<<<128, 128, 0, stream>>>(ps, ps2, 128, (float)NHIGH, w[18] + i * 128,
                                      w[19] + i * 128, sc, sh);
    k_linear_bn<128, 128, true><<<nb((long long)NHIGH * 128), 256, 0, stream>>>(
        S2, sc, sh, w[20] + i * 16384, w[21] + i * 128, S0, NHIGH);
    k_linear_bn<128, 128, true><<<nb((long long)NHIGH * 128), 256, 0, stream>>>(
        S2, sc, sh, w[22] + i * 16384, w[23] + i * 128, S1, NHIGH);
    k_gat_hh<2, false><<<NHIGH, 64, 0, stream>>>(S0, S1, w[24] + i * 128,
                                                 w[25] + i * 128, rpH, colH, S2);
  }

  // ---- Stage 5: g5 ----
  k_bn_part<<<100, 256, 0, stream>>>(S2, 128, 2, ps, ps2);
  k_bn_fin<<<128, 128, 0, stream>>>(ps, ps2, 128, (float)NHIGH, w[18] + 384,
                                    w[19] + 384, sc, sh);
  k_linear_bn<128, 64, true><<<nb((long long)NHIGH * 64), 256, 0, stream>>>(
      S2, sc, sh, w[26], w[27], S0, NHIGH);
  k_linear_bn<128, 64, true><<<nb((long long)NHIGH * 64), 256, 0, stream>>>(
      S2, sc, sh, w[28], w[29], S1, NHIGH);
  k_gat_hh<1, true><<<NHIGH, 64, 0, stream>>>(S0, S1, w[30], w[31], rpH, colH, S2);

  // ---- Stage 6: MLP (final writes d_out directly) ----
  k_linear<64, 64, true><<<nb((long long)NHIGH * 64), 256, 0, stream>>>(
      S2, w[32], w[33], S0, NHIGH);
  k_linear<64, 32, true><<<nb((long long)NHIGH * 32), 256, 0, stream>>>(
      S0, w[34], w[35], S1, NHIGH);
  k_linear<32, 1, false><<<nb((long long)NHIGH), 256, 0, stream>>>(
      S1, w[36], w[37], (float*)d_out, NHIGH);
}

// Round 11
// 2215.085 us; speedup vs baseline: 2.6672x; 1.8405x over previous
//
#include <hip/hip_runtime.h>

#define NLOW  8000
#define NHIGH 50000
#define NL25  200000
#define ELL   32000
#define ELH   1250000
#define EHH   800000

__global__ void k_fill_out(float* __restrict__ o, int n, float v) {
  int i = blockIdx.x * 256 + threadIdx.x;
  if (i < n) o[i] = v;
}

// ---------------- Stage 1: fused GCN ----------------
__global__ void k_init_deg(float* __restrict__ deg) {
  int i = blockIdx.x * 256 + threadIdx.x;
  if (i < NLOW) deg[i] = 1.0f;
}
__global__ void k_gcn_deg(const int* __restrict__ ei, float* __restrict__ deg) {
  int e = blockIdx.x * 256 + threadIdx.x;
  if (e >= ELL) return;
  int d = ei[ELL + e];
  if (d >= 0 && d < NLOW) atomicAdd(&deg[d], 1.0f);
}
__global__ void k_xa_init(const float* __restrict__ x, const float* __restrict__ deg,
                          float* __restrict__ xa) {
  int i = blockIdx.x * 256 + threadIdx.x;
  if (i >= NLOW * 125) return;
  xa[i] = x[i] / deg[i / 125];
}
__global__ void k_xa_edge(const float* __restrict__ x, const int* __restrict__ ei,
                          const float* __restrict__ deg, float* __restrict__ xa) {
  int gid = blockIdx.x * 256 + threadIdx.x;
  if (gid >= ELL * 125) return;
  int e = gid / 125, k = gid - e * 125;
  int s = ei[e], d = ei[ELL + e];
  if (s < 0 || s >= NLOW || d < 0 || d >= NLOW) return;
  float nrm = rsqrtf(deg[s]) * rsqrtf(deg[d]);
  atomicAdd(&xa[d * 125 + k], nrm * x[s * 125 + k]);
}
// M[vk, sp*100+j] = sum_c W[v,k,c*25+sp] * Wl[v*25+c, j]
__global__ void k_prep_M(const float* __restrict__ W, const float* __restrict__ Wl,
                         float* __restrict__ M) {
  int gid = blockIdx.x * 256 + threadIdx.x;
  if (gid >= 125 * 2500) return;
  int vk = gid / 2500, r = gid - vk * 2500, sp = r / 100, j = r - sp * 100;
  int v = vk / 25;
  float acc = 0.f;
#pragma unroll
  for (int c = 0; c < 25; c++)
    acc = fmaf(W[vk * 625 + c * 25 + sp], Wl[(v * 25 + c) * 100 + j], acc);
  M[gid] = acc;
}
__global__ void k_prep_b2(const float* __restrict__ b, const float* __restrict__ Wl,
                          const float* __restrict__ bl, float* __restrict__ b2) {
  int gid = blockIdx.x * 256 + threadIdx.x;
  if (gid >= 2500) return;
  int sp = gid / 100, j = gid - sp * 100;
  float acc = bl[j];
  for (int v = 0; v < 5; v++)
#pragma unroll
    for (int c = 0; c < 25; c++)
      acc = fmaf(b[v * 625 + c * 25 + sp], Wl[(v * 25 + c) * 100 + j], acc);
  b2[gid] = acc;
}

// Tiled GEMM: out[n, b] = sum_k xa[n,k]*M[k, cm(b)] + b2[cm(b)], b in [0,1250)
__global__ void k_hlT_gemm(const float* __restrict__ A, const float* __restrict__ M,
                           const float* __restrict__ b2v, int pass,
                           float* __restrict__ out) {
  __shared__ float As[32 * 65];
  __shared__ float Bs[32 * 68];
  int t = threadIdx.x;
  int tx = t & 15, ty = t >> 4;
  int row0 = blockIdx.x * 64, col0 = blockIdx.y * 64;
  float acc[4][4];
#pragma unroll
  for (int i = 0; i < 4; i++)
#pragma unroll
    for (int j = 0; j < 4; j++) acc[i][j] = 0.f;
  for (int k0 = 0; k0 < 125; k0 += 32) {
    int kw = 125 - k0; if (kw > 32) kw = 32;
    for (int l = t; l < 64 * 32; l += 256) {
      int r = l >> 5, kk = l & 31;
      As[kk * 65 + r] = (kk < kw) ? A[(size_t)(row0 + r) * 125 + k0 + kk] : 0.f;
    }
    for (int l = t; l < 32 * 64; l += 256) {
      int kk = l >> 6, bb = l & 63;
      int b = col0 + bb;
      float v = 0.f;
      if (kk < kw && b < 1250) {
        int cm = (b / 50) * 100 + 50 * pass + (b % 50);
        v = M[(size_t)(k0 + kk) * 2500 + cm];
      }
      Bs[kk * 68 + bb] = v;
    }
    __syncthreads();
#pragma unroll 8
    for (int kk = 0; kk < 32; kk++) {
      float a0 = As[kk * 65 + ty * 4 + 0];
      float a1 = As[kk * 65 + ty * 4 + 1];
      float a2 = As[kk * 65 + ty * 4 + 2];
      float a3 = As[kk * 65 + ty * 4 + 3];
      float b0 = Bs[kk * 68 + tx * 4 + 0];
      float b1 = Bs[kk * 68 + tx * 4 + 1];
      float b2x = Bs[kk * 68 + tx * 4 + 2];
      float b3 = Bs[kk * 68 + tx * 4 + 3];
      acc[0][0] = fmaf(a0, b0, acc[0][0]); acc[0][1] = fmaf(a0, b1, acc[0][1]);
      acc[0][2] = fmaf(a0, b2x, acc[0][2]); acc[0][3] = fmaf(a0, b3, acc[0][3]);
      acc[1][0] = fmaf(a1, b0, acc[1][0]); acc[1][1] = fmaf(a1, b1, acc[1][1]);
      acc[1][2] = fmaf(a1, b2x, acc[1][2]); acc[1][3] = fmaf(a1, b3, acc[1][3]);
      acc[2][0] = fmaf(a2, b0, acc[2][0]); acc[2][1] = fmaf(a2, b1, acc[2][1]);
      acc[2][2] = fmaf(a2, b2x, acc[2][2]); acc[2][3] = fmaf(a2, b3, acc[2][3]);
      acc[3][0] = fmaf(a3, b0, acc[3][0]); acc[3][1] = fmaf(a3, b1, acc[3][1]);
      acc[3][2] = fmaf(a3, b2x, acc[3][2]); acc[3][3] = fmaf(a3, b3, acc[3][3]);
    }
    __syncthreads();
  }
#pragma unroll
  for (int i = 0; i < 4; i++) {
    int r = row0 + ty * 4 + i;
#pragma unroll
    for (int j = 0; j < 4; j++) {
      int b = col0 + tx * 4 + j;
      if (b < 1250) {
        int cm = (b / 50) * 100 + 50 * pass + (b % 50);
        out[(size_t)r * 1250 + b] = acc[i][j] + b2v[cm];
      }
    }
  }
}

// ---- Generic node-feature GEMM with optional fused BN(+ReLU) on input and ReLU on out.
// out[r, col0+cc] = sum_k act(X[r,k]) * W[k, col], act(x) = INRELU? max(x*sc+sh,0) : ...
// grid: (ceil(n/64), COUT/64); COUT passed as arg (W row stride).
template <int CIN, bool BN, bool INRELU, bool OUTRELU>
__global__ void k_gemm_lin(const float* __restrict__ X, const float* __restrict__ sc,
                           const float* __restrict__ sh, const float* __restrict__ W,
                           const float* __restrict__ bias, float* __restrict__ out,
                           int n, int COUT) {
  __shared__ float As[32 * 65];
  __shared__ float Bs[32 * 68];
  int t = threadIdx.x;
  int tx = t & 15, ty = t >> 4;
  int row0 = blockIdx.x * 64, col0 = blockIdx.y * 64;
  float acc[4][4];
#pragma unroll
  for (int i = 0; i < 4; i++)
#pragma unroll
    for (int j = 0; j < 4; j++) acc[i][j] = 0.f;
  for (int k0 = 0; k0 < CIN; k0 += 32) {
    int kw = CIN - k0; if (kw > 32) kw = 32;
    for (int l = t; l < 64 * 32; l += 256) {
      int r = l >> 5, kk = l & 31;
      float v = 0.f;
      int rr = row0 + r;
      if (kk < kw && rr < n) {
        int k = k0 + kk;
        v = X[(size_t)rr * CIN + k];
        if (BN) v = fmaf(v, sc[k], sh[k]);
        if (INRELU) v = fmaxf(v, 0.f);
      }
      As[kk * 65 + r] = v;
    }
    for (int l = t; l < 32 * 64; l += 256) {
      int kk = l >> 6, cc = l & 63;
      Bs[kk * 68 + cc] = (kk < kw) ? W[(size_t)(k0 + kk) * COUT + col0 + cc] : 0.f;
    }
    __syncthreads();
#pragma unroll 8
    for (int kk = 0; kk < 32; kk++) {
      float a0 = As[kk * 65 + ty * 4 + 0];
      float a1 = As[kk * 65 + ty * 4 + 1];
      float a2 = As[kk * 65 + ty * 4 + 2];
      float a3 = As[kk * 65 + ty * 4 + 3];
      float b0 = Bs[kk * 68 + tx * 4 + 0];
      float b1 = Bs[kk * 68 + tx * 4 + 1];
      float b2x = Bs[kk * 68 + tx * 4 + 2];
      float b3 = Bs[kk * 68 + tx * 4 + 3];
      acc[0][0] = fmaf(a0, b0, acc[0][0]); acc[0][1] = fmaf(a0, b1, acc[0][1]);
      acc[0][2] = fmaf(a0, b2x, acc[0][2]); acc[0][3] = fmaf(a0, b3, acc[0][3]);
      acc[1][0] = fmaf(a1, b0, acc[1][0]); acc[1][1] = fmaf(a1, b1, acc[1][1]);
      acc[1][2] = fmaf(a1, b2x, acc[1][2]); acc[1][3] = fmaf(a1, b3, acc[1][3]);
      acc[2][0] = fmaf(a2, b0, acc[2][0]); acc[2][1] = fmaf(a2, b1, acc[2][1]);
      acc[2][2] = fmaf(a2, b2x, acc[2][2]); acc[2][3] = fmaf(a2, b3, acc[2][3]);
      acc[3][0] = fmaf(a3, b0, acc[3][0]); acc[3][1] = fmaf(a3, b1, acc[3][1]);
      acc[3][2] = fmaf(a3, b2x, acc[3][2]); acc[3][3] = fmaf(a3, b3, acc[3][3]);
    }
    __syncthreads();
  }
#pragma unroll
  for (int i = 0; i < 4; i++) {
    int r = row0 + ty * 4 + i;
    if (r >= n) continue;
#pragma unroll
    for (int j = 0; j < 4; j++) {
      int c = col0 + tx * 4 + j;
      float v = acc[i][j] + bias[c];
      if (OUTRELU) v = fmaxf(v, 0.f);
      out[(size_t)r * COUT + c] = v;
    }
  }
}

// ---------------- CSR build ----------------
__global__ void k_hist(const int* __restrict__ dst, int E, int* __restrict__ cnt) {
  int e = blockIdx.x * 256 + threadIdx.x;
  if (e >= E) return;
  int d = dst[e];
  if (d >= 0 && d < NHIGH) atomicAdd(&cnt[d], 1);
}
__global__ void k_scan1(const int* __restrict__ cnt, int* __restrict__ rp,
                        int* __restrict__ part, int N) {
  __shared__ int sh[256];
  int i = blockIdx.x * 256 + threadIdx.x;
  int v = (i < N) ? cnt[i] : 0;
  sh[threadIdx.x] = v;
  __syncthreads();
  for (int off = 1; off < 256; off <<= 1) {
    int t = (threadIdx.x >= off) ? sh[threadIdx.x - off] : 0;
    __syncthreads();
    sh[threadIdx.x] += t;
    __syncthreads();
  }
  if (i < N) rp[i] = sh[threadIdx.x] - v;
  if (threadIdx.x == 255) part[blockIdx.x] = sh[255];
}
__global__ void k_scan2(int* __restrict__ part, int nb) {
  __shared__ int sh[256];
  int v = (threadIdx.x < nb) ? part[threadIdx.x] : 0;
  sh[threadIdx.x] = v;
  __syncthreads();
  for (int off = 1; off < 256; off <<= 1) {
    int t = (threadIdx.x >= off) ? sh[threadIdx.x - off] : 0;
    __syncthreads();
    sh[threadIdx.x] += t;
    __syncthreads();
  }
  if (threadIdx.x < nb) part[threadIdx.x] = sh[threadIdx.x] - v;
}
__global__ void k_scan3(int* __restrict__ rp, const int* __restrict__ part, int N, int E) {
  int i = blockIdx.x * 256 + threadIdx.x;
  if (i < N) rp[i] += part[i / 256];
  if (i == 0) rp[N] = E;
}
__global__ void k_csr_scatter(const int* __restrict__ src, const int* __restrict__ dst,
                              const int* __restrict__ rp, int* __restrict__ fil,
                              int* __restrict__ col, int E) {
  int e = blockIdx.x * 256 + threadIdx.x;
  if (e >= E) return;
  int d = dst[e];
  if (d < 0 || d >= NHIGH) return;
  int pos = rp[d] + atomicAdd(&fil[d], 1);
  if (pos >= 0 && pos < E) col[pos] = src[e];
}

// ---------------- Stage 2: bipartite GATv2 (shfl logits) ----------------
__global__ void k_gat_th2(const float* __restrict__ hl50, const float* __restrict__ z,
                          const float* __restrict__ wr, const float* __restrict__ br,
                          const float* __restrict__ att, const int* __restrict__ rp,
                          const int* __restrict__ col, int pass,
                          float* __restrict__ acc25) {
  __shared__ float slog[1024];
  __shared__ float shr[50], satt[50], sden[2], sacc[50];
  int d = blockIdx.x, lane = threadIdx.x;
  int beg = rp[d];
  int deg = rp[d + 1] - beg;
  if (beg < 0) beg = 0;
  if (deg < 0) deg = 0;
  if (deg > 512) deg = 512;
  if (beg + deg > ELH) deg = (ELH - beg > 0) ? (ELH - beg) : 0;
  float zd = z[d];
  if (lane < 50) {
    int j = 50 * pass + lane;
    shr[lane] = fmaf(zd, wr[j], br[j]);
    satt[lane] = att[j];
  }
  __syncthreads();
  int g = lane >> 5, cc = lane & 31;
  for (int i = 0; i < deg; i++) {
    int s = col[beg + i];
    if (s < 0 || s >= NL25) s = 0;
    float p = 0.f;
    if (cc < 25) {
      float e = hl50[(size_t)s * 50 + g * 25 + cc] + shr[g * 25 + cc];
      e = (e > 0.f) ? e : 0.2f * e;
      p = e * satt[g * 25 + cc];
    }
#pragma unroll
    for (int off = 16; off > 0; off >>= 1) p += __shfl_xor(p, off, 64);
    if (cc == 0) slog[i * 2 + g] = p;
  }
  __syncthreads();
  if (lane < 2) {
    float m = -3.0e38f;
    for (int i = 0; i < deg; i++) m = fmaxf(m, slog[i * 2 + lane]);
    float den = 0.f;
    for (int i = 0; i < deg; i++) {
      float a = expf(slog[i * 2 + lane] - m);
      slog[i * 2 + lane] = a;
      den += a;
    }
    sden[lane] = fmaxf(den, 1e-16f);
  }
  __syncthreads();
  if (lane < 50) {
    int hh = lane / 25;
    float a = 0.f;
    for (int i = 0; i < deg; i++) {
      int s = col[beg + i];
      if (s < 0 || s >= NL25) s = 0;
      a = fmaf(slog[i * 2 + hh], hl50[(size_t)s * 50 + lane], a);
    }
    sacc[lane] = a / sden[hh];
  }
  __syncthreads();
  if (lane < 25) {
    float contrib = sacc[lane] + sacc[25 + lane];
    if (pass == 0) acc25[d * 25 + lane] = contrib;
    else           acc25[d * 25 + lane] += contrib;
  }
}
__global__ void k_th_fin(const float* __restrict__ acc25, const int* __restrict__ rp,
                         const float* __restrict__ bias, const float* __restrict__ z,
                         float* __restrict__ x26) {
  int gid = blockIdx.x * 256 + threadIdx.x;
  int node = gid / 26, j = gid - node * 26;
  if (node >= NHIGH) return;
  if (j == 0) {
    x26[node * 26] = z[node];
  } else {
    int dg = rp[node + 1] - rp[node];
    if (dg < 1) dg = 1;
    x26[node * 26 + j] = acc25[node * 25 + j - 1] / (4.0f * (float)dg) + bias[j - 1];
  }
}

// ---------------- high-res GATv2 (coalesced logits via shfl) ----------------
template <int H, bool RELU>
__global__ void k_gat_hh(const float* __restrict__ hl, const float* __restrict__ hr,
                         const float* __restrict__ att, const float* __restrict__ bias,
                         const int* __restrict__ rp, const int* __restrict__ col,
                         float* __restrict__ out) {
  const int F = H * 64;
  __shared__ float slog[260 * H];
  __shared__ float shr[F];
  __shared__ float satt[F];
  __shared__ float sden[H];
  int d = blockIdx.x, lane = threadIdx.x;
  int beg = rp[d];
  int deg = rp[d + 1] - beg;
  if (beg < 0) beg = 0;
  if (deg < 0) deg = 0;
  if (deg > 258) deg = 258;
  if (beg + deg > EHH) deg = (EHH - beg > 0) ? (EHH - beg) : 0;
  int tot = deg + 1;  // + self loop
  for (int j = lane; j < F; j += 64) {
    shr[j] = hr[(size_t)d * F + j];
    satt[j] = att[j];
  }
  __syncthreads();
  for (int i = 0; i < tot; i++) {
    int s = (i < deg) ? col[beg + i] : d;
    if (s < 0 || s >= NHIGH) s = 0;
    const float* row = hl + (size_t)s * F;
    float e0 = row[lane] + shr[lane];
    e0 = (e0 > 0.f) ? e0 : 0.2f * e0;
    float p0 = e0 * satt[lane];
    if (H == 2) {
      float e1 = row[64 + lane] + shr[64 + lane];
      e1 = (e1 > 0.f) ? e1 : 0.2f * e1;
      float p1 = e1 * satt[64 + lane];
#pragma unroll
      for (int off = 32; off > 0; off >>= 1) {
        p0 += __shfl_xor(p0, off, 64);
        p1 += __shfl_xor(p1, off, 64);
      }
      if (lane == 0) { slog[i * 2] = p0; slog[i * 2 + 1] = p1; }
    } else {
#pragma unroll
      for (int off = 32; off > 0; off >>= 1) p0 += __shfl_xor(p0, off, 64);
      if (lane == 0) slog[i] = p0;
    }
  }
  __syncthreads();
  if (lane < H) {
    float m = -3.0e38f;
    for (int i = 0; i < tot; i++) m = fmaxf(m, slog[i * H + lane]);
    float den = 0.f;
    for (int i = 0; i < tot; i++) {
      float a = expf(slog[i * H + lane] - m);
      slog[i * H + lane] = a;
      den += a;
    }
    sden[lane] = fmaxf(den, 1e-16f) * (float)tot;
  }
  __syncthreads();
  int c = lane;
  float acc[H];
#pragma unroll
  for (int h = 0; h < H; h++) acc[h] = 0.f;
  for (int i = 0; i < tot; i++) {
    int s = (i < deg) ? col[beg + i] : d;
    if (s < 0 || s >= NHIGH) s = 0;
#pragma unroll
    for (int h = 0; h < H; h++)
      acc[h] += slog[i * H + h] * hl[(size_t)s * F + h * 64 + c];
  }
#pragma unroll
  for (int h = 0; h < H; h++) {
    float v = acc[h] / sden[h] + bias[h * 64 + c];
    if (RELU) v = fmaxf(v, 0.f);
    out[(size_t)d * F + h * 64 + c] = v;
  }
}

// ---------------- BatchNorm: parallel partials + f64 finalize -> scale/shift ----------------
__global__ void k_bn_part(const float* __restrict__ x, int C, int tpc,
                          float* __restrict__ ps, float* __restrict__ ps2) {
  int gch = blockIdx.x, t = threadIdx.x;
  int c = t % C, sub = t / C;
  float s = 0.f, s2 = 0.f;
  if (sub < tpc) {
    for (int r = gch * 500 + sub; r < gch * 500 + 500; r += tpc) {
      float v = x[(size_t)r * C + c];
      s += v;
      s2 = fmaf(v, v, s2);
    }
  }
  __shared__ float ls[256], ls2[256];
  ls[t] = s; ls2[t] = s2;
  __syncthreads();
  if (t < C) {
    float a = 0.f, a2 = 0.f;
    for (int u = 0; u < tpc; u++) { a += ls[u * C + t]; a2 += ls2[u * C + t]; }
    ps[gch * C + t] = a;
    ps2[gch * C + t] = a2;
  }
}
__global__ void k_bn_fin(const float* __restrict__ ps, const float* __restrict__ ps2,
                         int C, float n, const float* __restrict__ g,
                         const float* __restrict__ b, float* __restrict__ sc,
                         float* __restrict__ sh) {
  int c = blockIdx.x, t = threadIdx.x;
  __shared__ double ds[128], ds2[128];
  double a = 0, a2 = 0;
  for (int q = t; q < 100; q += 128) { a += ps[q * C + c]; a2 += ps2[q * C + c]; }
  ds[t] = a; ds2[t] = a2;
  __syncthreads();
  for (int off = 64; off > 0; off >>= 1) {
    if (t < off) { ds[t] += ds[t + off]; ds2[t] += ds2[t + off]; }
    __syncthreads();
  }
  if (t == 0) {
    double m = ds[0] / n;
    double v = ds2[0] / n - m * m;
    if (v < 0) v = 0;
    float scale = g[c] * rsqrtf((float)v + 1e-5f);
    sc[c] = scale;
    sh[c] = b[c] - (float)m * scale;
  }
}

// small naive linear for MLP tails
template <int CIN, int COUT, bool RELU>
__global__ void k_linear(const float* __restrict__ x, const float* __restrict__ W,
                         const float* __restrict__ b, float* __restrict__ y, int n) {
  long long gid = (long long)blockIdx.x * 256 + threadIdx.x;
  int node = (int)(gid / COUT);
  int j = (int)(gid - (long long)node * COUT);
  if (node >= n) return;
  const float* xr = x + (size_t)node * CIN;
  float acc = b[j];
#pragma unroll 4
  for (int k = 0; k < CIN; k++) acc = fmaf(xr[k], W[k * COUT + j], acc);
  if (RELU) acc = fmaxf(acc, 0.f);
  y[(size_t)node * COUT + j] = acc;
}

extern "C" void kernel_launch(void* const* d_in, const int* in_sizes, int n_in,
                              void* d_out, int out_size, void* d_ws, size_t ws_size,
                              hipStream_t stream) {
  auto nb = [](long long t) { return dim3((unsigned)((t + 255) / 256)); };
  static const int FSZ[38] = {
      1000000, 50000, 78125, 3125, 12500, 100, 100, 100, 100, 25, 26, 26,
      3328, 128, 3328, 128, 128, 128, 512, 512, 49152, 384, 49152, 384, 384,
      384, 8192, 64, 8192, 64, 64, 64, 4096, 64, 2048, 32, 32, 1};
  static const int ISZ[4] = {64000, 1250000, 1250000, 1600000};
  if (n_in != 42) {
    k_fill_out<<<nb(out_size), 256, 0, stream>>>((float*)d_out, out_size, 500000.0f);
    return;
  }
  bool szok = true;
  for (int i = 0; i < 38; i++) szok &= (in_sizes[i] == FSZ[i]);
  for (int i = 0; i < 4; i++) szok &= (in_sizes[38 + i] == ISZ[i]);
  if (!szok) {
    k_fill_out<<<nb(out_size), 256, 0, stream>>>((float*)d_out, out_size, 600000.0f);
    return;
  }
  const size_t REQUIRED = 20146000ull * 4ull;
  if (ws_size < REQUIRED) {
    hipMemsetAsync(d_out, 0, (size_t)out_size * 4, stream);
    return;
  }

  const float* w[38];
  for (int i = 0; i < 38; i++) w[i] = (const float*)d_in[i];  // f32 (verified r6/r9)
  const int* ei_ll = (const int*)d_in[38];  // int32 (verified by r9/r10 probes)
  const int* s_l2h = (const int*)d_in[39];
  const int* d_l2h = (const int*)d_in[40];
  const int* ei_hh = (const int*)d_in[41];

  float* ws = (float*)d_ws;
  float* S0 = ws;                       // [0, 6.4M)
  float* S1 = ws + 6400000;             // [6.4M, 12.8M)
  float* S2 = ws + 12800000;            // [12.8M, 19.2M)
  // Stage-1/2 aliases (disjoint lifetimes vs S-slots):
  float* hl50  = ws;                    // [10,000,000]
  float* acc25 = ws + 10000000;         // [1,250,000]
  int*  rpT  = (int*)(ws + 11300000);   // [50,001]
  int*  filT = (int*)(ws + 11360000);   // [50,000]
  int*  colT = (int*)(ws + 11450000);   // [1,250,000] -> 12.7M
  float* xa  = ws + 12800000;           // [1,000,000]
  float* Mt  = ws + 13800000;           // [312,500]
  float* b2  = ws + 14112500;           // [2,500]
  float* x26 = ws + 14200000;           // [1,300,000] (dead before S2 written)
  // Persistent:
  int*  rpH  = (int*)(ws + 19200000);   // [50,001]
  int*  filH = (int*)(ws + 19260000);   // [50,000]
  int*  colH = (int*)(ws + 19310000);   // [800,000] -> 20,110,000
  float* deg = ws + 20110000;           // [8,000]
  float* sc  = ws + 20118000;           // [128]
  float* sh  = ws + 20118128;           // [128]
  int*  part = (int*)(ws + 20118256);   // [512]
  float* ps   = ws + 20120000;          // [12,800]
  float* ps2  = ws + 20132800;          // [12,800] -> 20,145,600

  // ---- CSR for both graphs ----
  auto build_csr = [&](const int* src, const int* dst, int E, int* rp, int* fil,
                       int* col) {
    hipMemsetAsync(fil, 0, NHIGH * 4, stream);
    k_hist<<<nb(E), 256, 0, stream>>>(dst, E, fil);
    int nblk = (NHIGH + 255) / 256;
    k_scan1<<<nblk, 256, 0, stream>>>(fil, rp, part, NHIGH);
    k_scan2<<<1, 256, 0, stream>>>(part, nblk);
    k_scan3<<<nb(NHIGH), 256, 0, stream>>>(rp, part, NHIGH, E);
    hipMemsetAsync(fil, 0, NHIGH * 4, stream);
    k_csr_scatter<<<nb(E), 256, 0, stream>>>(src, dst, rp, fil, col, E);
  };
  build_csr(s_l2h, d_l2h, ELH, rpT, filT, colT);
  build_csr(ei_hh, ei_hh + EHH, EHH, rpH, filH, colH);

  // ---- Stage 1: GCN fold ----
  k_init_deg<<<nb(NLOW), 256, 0, stream>>>(deg);
  k_gcn_deg<<<nb(ELL), 256, 0, stream>>>(ei_ll, deg);
  k_xa_init<<<nb(NLOW * 125), 256, 0, stream>>>(w[0], deg, xa);
  k_xa_edge<<<nb((long long)ELL * 125), 256, 0, stream>>>(w[0], ei_ll, deg, xa);
  k_prep_M<<<nb(125 * 2500), 256, 0, stream>>>(w[2], w[4], Mt);
  k_prep_b2<<<nb(2500), 256, 0, stream>>>(w[3], w[4], w[5], b2);

  // ---- Stage 2: th GATv2, 2 head-passes ----
  for (int p = 0; p < 2; p++) {
    k_hlT_gemm<<<dim3(125, 20), 256, 0, stream>>>(xa, Mt, b2, p, hl50);
    k_gat_th2<<<NHIGH, 64, 0, stream>>>(hl50, w[1], w[6], w[7], w[8], rpT, colT, p,
                                        acc25);
  }
  k_th_fin<<<nb((long long)NHIGH * 26), 256, 0, stream>>>(acc25, rpT, w[9], w[1], x26);

  const dim3 g1(782, 2), g2(782, 1);

  // ---- Stage 3: bn0 + g1 ----
  k_bn_part<<<100, 256, 0, stream>>>(x26, 26, 9, ps, ps2);
  k_bn_fin<<<26, 128, 0, stream>>>(ps, ps2, 26, (float)NHIGH, w[10], w[11], sc, sh);
  k_gemm_lin<26, true, false, false><<<g1, 256, 0, stream>>>(
      x26, sc, sh, w[12], w[13], S0, NHIGH, 128);
  k_gemm_lin<26, true, false, false><<<g1, 256, 0, stream>>>(
      x26, sc, sh, w[14], w[15], S1, NHIGH, 128);
  k_gat_hh<2, false><<<NHIGH, 64, 0, stream>>>(S0, S1, w[16], w[17], rpH, colH, S2);

  // ---- Stage 4: 3x gm ----
  for (int i = 0; i < 3; i++) {
    k_bn_part<<<100, 256, 0, stream>>>(S2, 128, 2, ps, ps2);
    k_bn_fin<<<128, 128, 0, stream>>>(ps, ps2, 128, (float)NHIGH, w[18] + i * 128,
                                      w[19] + i * 128, sc, sh);
    k_gemm_lin<128, true, true, false><<<g1, 256, 0, stream>>>(
        S2, sc, sh, w[20] + i * 16384, w[21] + i * 128, S0, NHIGH, 128);
    k_gemm_lin<128, true, true, false><<<g1, 256, 0, stream>>>(
        S2, sc, sh, w[22] + i * 16384, w[23] + i * 128, S1, NHIGH, 128);
    k_gat_hh<2, false><<<NHIGH, 64, 0, stream>>>(S0, S1, w[24] + i * 128,
                                                 w[25] + i * 128, rpH, colH, S2);
  }

  // ---- Stage 5: g5 ----
  k_bn_part<<<100, 256, 0, stream>>>(S2, 128, 2, ps, ps2);
  k_bn_fin<<<128, 128, 0, stream>>>(ps, ps2, 128, (float)NHIGH, w[18] + 384,
                                    w[19] + 384, sc, sh);
  k_gemm_lin<128, true, true, false><<<g2, 256, 0, stream>>>(
      S2, sc, sh, w[26], w[27], S0, NHIGH, 64);
  k_gemm_lin<128, true, true, false><<<g2, 256, 0, stream>>>(
      S2, sc, sh, w[28], w[29], S1, NHIGH, 64);
  k_gat_hh<1, true><<<NHIGH, 64, 0, stream>>>(S0, S1, w[30], w[31], rpH, colH, S2);

  // ---- Stage 6: MLP ----
  k_gemm_lin<64, false, false, true><<<g2, 256, 0, stream>>>(
      S2, sc, sh, w[32], w[33], S0, NHIGH, 64);
  k_linear<64, 32, true><<<nb((long long)NHIGH * 32), 256, 0, stream>>>(
      S0, w[34], w[35], S1, NHIGH);
  k_linear<32, 1, false><<<nb((long long)NHIGH), 256, 0, stream>>>(
      S1, w[36], w[37], (float*)d_out, NHIGH);
}

// Round 12
// 1975.944 us; speedup vs baseline: 2.9900x; 1.1210x over previous
//
#include <hip/hip_runtime.h>

#define NLOW  8000
#define NHIGH 50000
#define NL25  200000
#define ELL   32000
#define ELH   1250000
#define EHH   800000

__global__ void k_fill_out(float* __restrict__ o, int n, float v) {
  int i = blockIdx.x * 256 + threadIdx.x;
  if (i < n) o[i] = v;
}

// ---------------- Stage 1: fused GCN ----------------
__global__ void k_init_deg(float* __restrict__ deg) {
  int i = blockIdx.x * 256 + threadIdx.x;
  if (i < NLOW) deg[i] = 1.0f;
}
__global__ void k_gcn_deg(const int* __restrict__ ei, float* __restrict__ deg) {
  int e = blockIdx.x * 256 + threadIdx.x;
  if (e >= ELL) return;
  int d = ei[ELL + e];
  if (d >= 0 && d < NLOW) atomicAdd(&deg[d], 1.0f);
}
__global__ void k_xa_init(const float* __restrict__ x, const float* __restrict__ deg,
                          float* __restrict__ xa) {
  int i = blockIdx.x * 256 + threadIdx.x;
  if (i >= NLOW * 125) return;
  xa[i] = x[i] / deg[i / 125];
}
__global__ void k_xa_edge(const float* __restrict__ x, const int* __restrict__ ei,
                          const float* __restrict__ deg, float* __restrict__ xa) {
  int gid = blockIdx.x * 256 + threadIdx.x;
  if (gid >= ELL * 125) return;
  int e = gid / 125, k = gid - e * 125;
  int s = ei[e], d = ei[ELL + e];
  if (s < 0 || s >= NLOW || d < 0 || d >= NLOW) return;
  float nrm = rsqrtf(deg[s]) * rsqrtf(deg[d]);
  atomicAdd(&xa[d * 125 + k], nrm * x[s * 125 + k]);
}
// M[vk, sp*100+j] = sum_c W[v,k,c*25+sp] * Wl[v*25+c, j]
__global__ void k_prep_M(const float* __restrict__ W, const float* __restrict__ Wl,
                         float* __restrict__ M) {
  int gid = blockIdx.x * 256 + threadIdx.x;
  if (gid >= 125 * 2500) return;
  int vk = gid / 2500, r = gid - vk * 2500, sp = r / 100, j = r - sp * 100;
  int v = vk / 25;
  float acc = 0.f;
#pragma unroll
  for (int c = 0; c < 25; c++)
    acc = fmaf(W[vk * 625 + c * 25 + sp], Wl[(v * 25 + c) * 100 + j], acc);
  M[gid] = acc;
}
__global__ void k_prep_b2(const float* __restrict__ b, const float* __restrict__ Wl,
                          const float* __restrict__ bl, float* __restrict__ b2) {
  int gid = blockIdx.x * 256 + threadIdx.x;
  if (gid >= 2500) return;
  int sp = gid / 100, j = gid - sp * 100;
  float acc = bl[j];
  for (int v = 0; v < 5; v++)
#pragma unroll
    for (int c = 0; c < 25; c++)
      acc = fmaf(b[v * 625 + c * 25 + sp], Wl[(v * 25 + c) * 100 + j], acc);
  b2[gid] = acc;
}

// Tiled GEMM: out[n, b] = sum_k xa[n,k]*M[k, cm(b)] + b2[cm(b)], b in [0,1250)
__global__ void k_hlT_gemm(const float* __restrict__ A, const float* __restrict__ M,
                           const float* __restrict__ b2v, int pass,
                           float* __restrict__ out) {
  __shared__ float As[32 * 65];
  __shared__ float Bs[32 * 68];
  int t = threadIdx.x;
  int tx = t & 15, ty = t >> 4;
  int row0 = blockIdx.x * 64, col0 = blockIdx.y * 64;
  float acc[4][4];
#pragma unroll
  for (int i = 0; i < 4; i++)
#pragma unroll
    for (int j = 0; j < 4; j++) acc[i][j] = 0.f;
  for (int k0 = 0; k0 < 125; k0 += 32) {
    int kw = 125 - k0; if (kw > 32) kw = 32;
    for (int l = t; l < 64 * 32; l += 256) {
      int r = l >> 5, kk = l & 31;
      As[kk * 65 + r] = (kk < kw) ? A[(size_t)(row0 + r) * 125 + k0 + kk] : 0.f;
    }
    for (int l = t; l < 32 * 64; l += 256) {
      int kk = l >> 6, bb = l & 63;
      int b = col0 + bb;
      float v = 0.f;
      if (kk < kw && b < 1250) {
        int cm = (b / 50) * 100 + 50 * pass + (b % 50);
        v = M[(size_t)(k0 + kk) * 2500 + cm];
      }
      Bs[kk * 68 + bb] = v;
    }
    __syncthreads();
#pragma unroll 8
    for (int kk = 0; kk < 32; kk++) {
      float a0 = As[kk * 65 + ty * 4 + 0];
      float a1 = As[kk * 65 + ty * 4 + 1];
      float a2 = As[kk * 65 + ty * 4 + 2];
      float a3 = As[kk * 65 + ty * 4 + 3];
      float b0 = Bs[kk * 68 + tx * 4 + 0];
      float b1 = Bs[kk * 68 + tx * 4 + 1];
      float b2x = Bs[kk * 68 + tx * 4 + 2];
      float b3 = Bs[kk * 68 + tx * 4 + 3];
      acc[0][0] = fmaf(a0, b0, acc[0][0]); acc[0][1] = fmaf(a0, b1, acc[0][1]);
      acc[0][2] = fmaf(a0, b2x, acc[0][2]); acc[0][3] = fmaf(a0, b3, acc[0][3]);
      acc[1][0] = fmaf(a1, b0, acc[1][0]); acc[1][1] = fmaf(a1, b1, acc[1][1]);
      acc[1][2] = fmaf(a1, b2x, acc[1][2]); acc[1][3] = fmaf(a1, b3, acc[1][3]);
      acc[2][0] = fmaf(a2, b0, acc[2][0]); acc[2][1] = fmaf(a2, b1, acc[2][1]);
      acc[2][2] = fmaf(a2, b2x, acc[2][2]); acc[2][3] = fmaf(a2, b3, acc[2][3]);
      acc[3][0] = fmaf(a3, b0, acc[3][0]); acc[3][1] = fmaf(a3, b1, acc[3][1]);
      acc[3][2] = fmaf(a3, b2x, acc[3][2]); acc[3][3] = fmaf(a3, b3, acc[3][3]);
    }
    __syncthreads();
  }
#pragma unroll
  for (int i = 0; i < 4; i++) {
    int r = row0 + ty * 4 + i;
#pragma unroll
    for (int j = 0; j < 4; j++) {
      int b = col0 + tx * 4 + j;
      if (b < 1250) {
        int cm = (b / 50) * 100 + 50 * pass + (b % 50);
        out[(size_t)r * 1250 + b] = acc[i][j] + b2v[cm];
      }
    }
  }
}

// ---- Generic node-feature GEMM, fused BN(+ReLU) on input, ReLU on out.
template <int CIN, bool BN, bool INRELU, bool OUTRELU>
__global__ void k_gemm_lin(const float* __restrict__ X, const float* __restrict__ sc,
                           const float* __restrict__ sh, const float* __restrict__ W,
                           const float* __restrict__ bias, float* __restrict__ out,
                           int n, int COUT) {
  __shared__ float As[32 * 65];
  __shared__ float Bs[32 * 68];
  int t = threadIdx.x;
  int tx = t & 15, ty = t >> 4;
  int row0 = blockIdx.x * 64, col0 = blockIdx.y * 64;
  float acc[4][4];
#pragma unroll
  for (int i = 0; i < 4; i++)
#pragma unroll
    for (int j = 0; j < 4; j++) acc[i][j] = 0.f;
  for (int k0 = 0; k0 < CIN; k0 += 32) {
    int kw = CIN - k0; if (kw > 32) kw = 32;
    for (int l = t; l < 64 * 32; l += 256) {
      int r = l >> 5, kk = l & 31;
      float v = 0.f;
      int rr = row0 + r;
      if (kk < kw && rr < n) {
        int k = k0 + kk;
        v = X[(size_t)rr * CIN + k];
        if (BN) v = fmaf(v, sc[k], sh[k]);
        if (INRELU) v = fmaxf(v, 0.f);
      }
      As[kk * 65 + r] = v;
    }
    for (int l = t; l < 32 * 64; l += 256) {
      int kk = l >> 6, cc = l & 63;
      Bs[kk * 68 + cc] = (kk < kw) ? W[(size_t)(k0 + kk) * COUT + col0 + cc] : 0.f;
    }
    __syncthreads();
#pragma unroll 8
    for (int kk = 0; kk < 32; kk++) {
      float a0 = As[kk * 65 + ty * 4 + 0];
      float a1 = As[kk * 65 + ty * 4 + 1];
      float a2 = As[kk * 65 + ty * 4 + 2];
      float a3 = As[kk * 65 + ty * 4 + 3];
      float b0 = Bs[kk * 68 + tx * 4 + 0];
      float b1 = Bs[kk * 68 + tx * 4 + 1];
      float b2x = Bs[kk * 68 + tx * 4 + 2];
      float b3 = Bs[kk * 68 + tx * 4 + 3];
      acc[0][0] = fmaf(a0, b0, acc[0][0]); acc[0][1] = fmaf(a0, b1, acc[0][1]);
      acc[0][2] = fmaf(a0, b2x, acc[0][2]); acc[0][3] = fmaf(a0, b3, acc[0][3]);
      acc[1][0] = fmaf(a1, b0, acc[1][0]); acc[1][1] = fmaf(a1, b1, acc[1][1]);
      acc[1][2] = fmaf(a1, b2x, acc[1][2]); acc[1][3] = fmaf(a1, b3, acc[1][3]);
      acc[2][0] = fmaf(a2, b0, acc[2][0]); acc[2][1] = fmaf(a2, b1, acc[2][1]);
      acc[2][2] = fmaf(a2, b2x, acc[2][2]); acc[2][3] = fmaf(a2, b3, acc[2][3]);
      acc[3][0] = fmaf(a3, b0, acc[3][0]); acc[3][1] = fmaf(a3, b1, acc[3][1]);
      acc[3][2] = fmaf(a3, b2x, acc[3][2]); acc[3][3] = fmaf(a3, b3, acc[3][3]);
    }
    __syncthreads();
  }
#pragma unroll
  for (int i = 0; i < 4; i++) {
    int r = row0 + ty * 4 + i;
    if (r >= n) continue;
#pragma unroll
    for (int j = 0; j < 4; j++) {
      int c = col0 + tx * 4 + j;
      float v = acc[i][j] + bias[c];
      if (OUTRELU) v = fmaxf(v, 0.f);
      out[(size_t)r * COUT + c] = v;
    }
  }
}

// ---------------- CSR build ----------------
__global__ void k_hist(const int* __restrict__ dst, int E, int* __restrict__ cnt) {
  int e = blockIdx.x * 256 + threadIdx.x;
  if (e >= E) return;
  int d = dst[e];
  if (d >= 0 && d < NHIGH) atomicAdd(&cnt[d], 1);
}
__global__ void k_scan1(const int* __restrict__ cnt, int* __restrict__ rp,
                        int* __restrict__ part, int N) {
  __shared__ int sh[256];
  int i = blockIdx.x * 256 + threadIdx.x;
  int v = (i < N) ? cnt[i] : 0;
  sh[threadIdx.x] = v;
  __syncthreads();
  for (int off = 1; off < 256; off <<= 1) {
    int t = (threadIdx.x >= off) ? sh[threadIdx.x - off] : 0;
    __syncthreads();
    sh[threadIdx.x] += t;
    __syncthreads();
  }
  if (i < N) rp[i] = sh[threadIdx.x] - v;
  if (threadIdx.x == 255) part[blockIdx.x] = sh[255];
}
__global__ void k_scan2(int* __restrict__ part, int nb) {
  __shared__ int sh[256];
  int v = (threadIdx.x < nb) ? part[threadIdx.x] : 0;
  sh[threadIdx.x] = v;
  __syncthreads();
  for (int off = 1; off < 256; off <<= 1) {
    int t = (threadIdx.x >= off) ? sh[threadIdx.x - off] : 0;
    __syncthreads();
    sh[threadIdx.x] += t;
    __syncthreads();
  }
  if (threadIdx.x < nb) part[threadIdx.x] = sh[threadIdx.x] - v;
}
__global__ void k_scan3(int* __restrict__ rp, const int* __restrict__ part, int N, int E) {
  int i = blockIdx.x * 256 + threadIdx.x;
  if (i < N) rp[i] += part[i / 256];
  if (i == 0) rp[N] = E;
}
__global__ void k_csr_scatter(const int* __restrict__ src, const int* __restrict__ dst,
                              const int* __restrict__ rp, int* __restrict__ fil,
                              int* __restrict__ col, int E) {
  int e = blockIdx.x * 256 + threadIdx.x;
  if (e >= E) return;
  int d = dst[e];
  if (d < 0 || d >= NHIGH) return;
  int pos = rp[d] + atomicAdd(&fil[d], 1);
  if (pos >= 0 && pos < E) col[pos] = src[e];
}

// ---------------- Stage 2: bipartite GATv2, fused online softmax ----------------
// Heads 2p,2p+1 live in half-waves g=0,1; lane (g,cc) owns channel g*25+cc (cc<25).
__global__ void k_gat_th2(const float* __restrict__ hl50, const float* __restrict__ z,
                          const float* __restrict__ wr, const float* __restrict__ br,
                          const float* __restrict__ att, const int* __restrict__ rp,
                          const int* __restrict__ col, int pass,
                          float* __restrict__ acc25) {
  int d = blockIdx.x, lane = threadIdx.x;
  int beg = rp[d];
  int deg = rp[d + 1] - beg;
  if (beg < 0) beg = 0;
  if (deg < 0) deg = 0;
  if (beg + deg > ELH) deg = (ELH - beg > 0) ? (ELH - beg) : 0;
  float zd = z[d];
  int g = lane >> 5, cc = lane & 31;
  bool act = cc < 25;
  int ch = g * 25 + (act ? cc : 0);
  float hrv = 0.f, atv = 0.f;
  if (act) {
    int j = 50 * pass + ch;
    hrv = fmaf(zd, wr[j], br[j]);
    atv = att[j];
  }
  float m = -3.0e38f, den = 0.f, acc = 0.f;
  for (int i = 0; i < deg; i++) {
    int s = col[beg + i];
    if (s < 0 || s >= NL25) s = 0;
    float r = act ? hl50[(size_t)s * 50 + ch] : 0.f;
    float e = r + hrv;
    e = (e > 0.f) ? e : 0.2f * e;
    float p = act ? e * atv : 0.f;
#pragma unroll
    for (int off = 16; off > 0; off >>= 1) p += __shfl_xor(p, off, 64);
    // p is uniform within each 32-lane half (head logit). Online update:
    if (p > m) {
      float s_ = expf(m - p);
      den = fmaf(den, s_, 1.f);
      acc = fmaf(acc, s_, r);
      m = p;
    } else {
      float w_ = expf(p - m);
      den += w_;
      acc = fmaf(w_, r, acc);
    }
  }
  float v = acc / fmaxf(den, 1e-16f);
  float other = __shfl_down(v, 32, 64);  // head-1 partner channel
  if (lane < 25) {
    float contrib = v + other;
    if (pass == 0) acc25[d * 25 + lane] = contrib;
    else           acc25[d * 25 + lane] += contrib;
  }
}
__global__ void k_th_fin(const float* __restrict__ acc25, const int* __restrict__ rp,
                         const float* __restrict__ bias, const float* __restrict__ z,
                         float* __restrict__ x26) {
  int gid = blockIdx.x * 256 + threadIdx.x;
  int node = gid / 26, j = gid - node * 26;
  if (node >= NHIGH) return;
  if (j == 0) {
    x26[node * 26] = z[node];
  } else {
    int dg = rp[node + 1] - rp[node];
    if (dg < 1) dg = 1;
    x26[node * 26 + j] = acc25[node * 25 + j - 1] / (4.0f * (float)dg) + bias[j - 1];
  }
}

// ---------------- high-res GATv2: fused online softmax, single gather pass ----------------
template <int H, bool RELU>
__global__ void k_gat_hh(const float* __restrict__ hl, const float* __restrict__ hr,
                         const float* __restrict__ att, const float* __restrict__ bias,
                         const int* __restrict__ rp, const int* __restrict__ col,
                         float* __restrict__ out) {
  const int F = H * 64;
  int d = blockIdx.x, lane = threadIdx.x;
  int beg = rp[d];
  int deg = rp[d + 1] - beg;
  if (beg < 0) beg = 0;
  if (deg < 0) deg = 0;
  if (beg + deg > EHH) deg = (EHH - beg > 0) ? (EHH - beg) : 0;
  int tot = deg + 1;  // + self loop
  float hrv[H], atv[H], m[H], den[H], acc[H];
#pragma unroll
  for (int h = 0; h < H; h++) {
    hrv[h] = hr[(size_t)d * F + h * 64 + lane];
    atv[h] = att[h * 64 + lane];
    m[h] = -3.0e38f; den[h] = 0.f; acc[h] = 0.f;
  }
  for (int i = 0; i < tot; i++) {
    int s = (i < deg) ? col[beg + i] : d;
    if (s < 0 || s >= NHIGH) s = 0;
    const float* row = hl + (size_t)s * F;
    float r[H], p[H];
#pragma unroll
    for (int h = 0; h < H; h++) {
      r[h] = row[h * 64 + lane];
      float e = r[h] + hrv[h];
      e = (e > 0.f) ? e : 0.2f * e;
      p[h] = e * atv[h];
    }
#pragma unroll
    for (int off = 32; off > 0; off >>= 1) {
#pragma unroll
      for (int h = 0; h < H; h++) p[h] += __shfl_xor(p[h], off, 64);
    }
    // p[h] uniform across wave -> uniform branch per head
#pragma unroll
    for (int h = 0; h < H; h++) {
      if (p[h] > m[h]) {
        float s_ = expf(m[h] - p[h]);
        den[h] = fmaf(den[h], s_, 1.f);
        acc[h] = fmaf(acc[h], s_, r[h]);
        m[h] = p[h];
      } else {
        float w_ = expf(p[h] - m[h]);
        den[h] += w_;
        acc[h] = fmaf(w_, r[h], acc[h]);
      }
    }
  }
#pragma unroll
  for (int h = 0; h < H; h++) {
    float v = acc[h] / (fmaxf(den[h], 1e-16f) * (float)tot) + bias[h * 64 + lane];
    if (RELU) v = fmaxf(v, 0.f);
    out[(size_t)d * F + h * 64 + lane] = v;
  }
}

// ---------------- BatchNorm: parallel partials + f64 finalize -> scale/shift ----------------
__global__ void k_bn_part(const float* __restrict__ x, int C, int tpc,
                          float* __restrict__ ps, float* __restrict__ ps2) {
  int gch = blockIdx.x, t = threadIdx.x;
  int c = t % C, sub = t / C;
  float s = 0.f, s2 = 0.f;
  if (sub < tpc) {
    for (int r = gch * 500 + sub; r < gch * 500 + 500; r += tpc) {
      float v = x[(size_t)r * C + c];
      s += v;
      s2 = fmaf(v, v, s2);
    }
  }
  __shared__ float ls[256], ls2[256];
  ls[t] = s; ls2[t] = s2;
  __syncthreads();
  if (t < C) {
    float a = 0.f, a2 = 0.f;
    for (int u = 0; u < tpc; u++) { a += ls[u * C + t]; a2 += ls2[u * C + t]; }
    ps[gch * C + t] = a;
    ps2[gch * C + t] = a2;
  }
}
__global__ void k_bn_fin(const float* __restrict__ ps, const float* __restrict__ ps2,
                         int C, float n, const float* __restrict__ g,
                         const float* __restrict__ b, float* __restrict__ sc,
                         float* __restrict__ sh) {
  int c = blockIdx.x, t = threadIdx.x;
  __shared__ double ds[128], ds2[128];
  double a = 0, a2 = 0;
  for (int q = t; q < 100; q += 128) { a += ps[q * C + c]; a2 += ps2[q * C + c]; }
  ds[t] = a; ds2[t] = a2;
  __syncthreads();
  for (int off = 64; off > 0; off >>= 1) {
    if (t < off) { ds[t] += ds[t + off]; ds2[t] += ds2[t + off]; }
    __syncthreads();
  }
  if (t == 0) {
    double m = ds[0] / n;
    double v = ds2[0] / n - m * m;
    if (v < 0) v = 0;
    float scale = g[c] * rsqrtf((float)v + 1e-5f);
    sc[c] = scale;
    sh[c] = b[c] - (float)m * scale;
  }
}

// small naive linear for MLP tails
template <int CIN, int COUT, bool RELU>
__global__ void k_linear(const float* __restrict__ x, const float* __restrict__ W,
                         const float* __restrict__ b, float* __restrict__ y, int n) {
  long long gid = (long long)blockIdx.x * 256 + threadIdx.x;
  int node = (int)(gid / COUT);
  int j = (int)(gid - (long long)node * COUT);
  if (node >= n) return;
  const float* xr = x + (size_t)node * CIN;
  float acc = b[j];
#pragma unroll 4
  for (int k = 0; k < CIN; k++) acc = fmaf(xr[k], W[k * COUT + j], acc);
  if (RELU) acc = fmaxf(acc, 0.f);
  y[(size_t)node * COUT + j] = acc;
}

extern "C" void kernel_launch(void* const* d_in, const int* in_sizes, int n_in,
                              void* d_out, int out_size, void* d_ws, size_t ws_size,
                              hipStream_t stream) {
  auto nb = [](long long t) { return dim3((unsigned)((t + 255) / 256)); };
  static const int FSZ[38] = {
      1000000, 50000, 78125, 3125, 12500, 100, 100, 100, 100, 25, 26, 26,
      3328, 128, 3328, 128, 128, 128, 512, 512, 49152, 384, 49152, 384, 384,
      384, 8192, 64, 8192, 64, 64, 64, 4096, 64, 2048, 32, 32, 1};
  static const int ISZ[4] = {64000, 1250000, 1250000, 1600000};
  if (n_in != 42) {
    k_fill_out<<<nb(out_size), 256, 0, stream>>>((float*)d_out, out_size, 500000.0f);
    return;
  }
  bool szok = true;
  for (int i = 0; i < 38; i++) szok &= (in_sizes[i] == FSZ[i]);
  for (int i = 0; i < 4; i++) szok &= (in_sizes[38 + i] == ISZ[i]);
  if (!szok) {
    k_fill_out<<<nb(out_size), 256, 0, stream>>>((float*)d_out, out_size, 600000.0f);
    return;
  }
  const size_t REQUIRED = 20146000ull * 4ull;
  if (ws_size < REQUIRED) {
    hipMemsetAsync(d_out, 0, (size_t)out_size * 4, stream);
    return;
  }

  const float* w[38];
  for (int i = 0; i < 38; i++) w[i] = (const float*)d_in[i];  // f32 (verified r6/r9)
  const int* ei_ll = (const int*)d_in[38];  // int32 (verified r9/r10)
  const int* s_l2h = (const int*)d_in[39];
  const int* d_l2h = (const int*)d_in[40];
  const int* ei_hh = (const int*)d_in[41];

  float* ws = (float*)d_ws;
  float* S0 = ws;                       // [0, 6.4M)
  float* S1 = ws + 6400000;             // [6.4M, 12.8M)
  float* S2 = ws + 12800000;            // [12.8M, 19.2M)
  // Stage-1/2 aliases (disjoint lifetimes vs S-slots):
  float* hl50  = ws;                    // [10,000,000]
  float* acc25 = ws + 10000000;         // [1,250,000]
  int*  rpT  = (int*)(ws + 11300000);   // [50,001]
  int*  filT = (int*)(ws + 11360000);   // [50,000]
  int*  colT = (int*)(ws + 11450000);   // [1,250,000] -> 12.7M
  float* xa  = ws + 12800000;           // [1,000,000]
  float* Mt  = ws + 13800000;           // [312,500]
  float* b2  = ws + 14112500;           // [2,500]
  float* x26 = ws + 14200000;           // [1,300,000] (dead before S2 written)
  // Persistent:
  int*  rpH  = (int*)(ws + 19200000);   // [50,001]
  int*  filH = (int*)(ws + 19260000);   // [50,000]
  int*  colH = (int*)(ws + 19310000);   // [800,000] -> 20,110,000
  float* deg = ws + 20110000;           // [8,000]
  float* sc  = ws + 20118000;           // [128]
  float* sh  = ws + 20118128;           // [128]
  int*  part = (int*)(ws + 20118256);   // [512]
  float* ps   = ws + 20120000;          // [12,800]
  float* ps2  = ws + 20132800;          // [12,800] -> 20,145,600

  // ---- CSR for both graphs ----
  auto build_csr = [&](const int* src, const int* dst, int E, int* rp, int* fil,
                       int* col) {
    hipMemsetAsync(fil, 0, NHIGH * 4, stream);
    k_hist<<<nb(E), 256, 0, stream>>>(dst, E, fil);
    int nblk = (NHIGH + 255) / 256;
    k_scan1<<<nblk, 256, 0, stream>>>(fil, rp, part, NHIGH);
    k_scan2<<<1, 256, 0, stream>>>(part, nblk);
    k_scan3<<<nb(NHIGH), 256, 0, stream>>>(rp, part, NHIGH, E);
    hipMemsetAsync(fil, 0, NHIGH * 4, stream);
    k_csr_scatter<<<nb(E), 256, 0, stream>>>(src, dst, rp, fil, col, E);
  };
  build_csr(s_l2h, d_l2h, ELH, rpT, filT, colT);
  build_csr(ei_hh, ei_hh + EHH, EHH, rpH, filH, colH);

  // ---- Stage 1: GCN fold ----
  k_init_deg<<<nb(NLOW), 256, 0, stream>>>(deg);
  k_gcn_deg<<<nb(ELL), 256, 0, stream>>>(ei_ll, deg);
  k_xa_init<<<nb(NLOW * 125), 256, 0, stream>>>(w[0], deg, xa);
  k_xa_edge<<<nb((long long)ELL * 125), 256, 0, stream>>>(w[0], ei_ll, deg, xa);
  k_prep_M<<<nb(125 * 2500), 256, 0, stream>>>(w[2], w[4], Mt);
  k_prep_b2<<<nb(2500), 256, 0, stream>>>(w[3], w[4], w[5], b2);

  // ---- Stage 2: th GATv2, 2 head-passes ----
  for (int p = 0; p < 2; p++) {
    k_hlT_gemm<<<dim3(125, 20), 256, 0, stream>>>(xa, Mt, b2, p, hl50);
    k_gat_th2<<<NHIGH, 64, 0, stream>>>(hl50, w[1], w[6], w[7], w[8], rpT, colT, p,
                                        acc25);
  }
  k_th_fin<<<nb((long long)NHIGH * 26), 256, 0, stream>>>(acc25, rpT, w[9], w[1], x26);

  const dim3 g1(782, 2), g2(782, 1);

  // ---- Stage 3: bn0 + g1 ----
  k_bn_part<<<100, 256, 0, stream>>>(x26, 26, 9, ps, ps2);
  k_bn_fin<<<26, 128, 0, stream>>>(ps, ps2, 26, (float)NHIGH, w[10], w[11], sc, sh);
  k_gemm_lin<26, true, false, false><<<g1, 256, 0, stream>>>(
      x26, sc, sh, w[12], w[13], S0, NHIGH, 128);
  k_gemm_lin<26, true, false, false><<<g1, 256, 0, stream>>>(
      x26, sc, sh, w[14], w[15], S1, NHIGH, 128);
  k_gat_hh<2, false><<<NHIGH, 64, 0, stream>>>(S0, S1, w[16], w[17], rpH, colH, S2);

  // ---- Stage 4: 3x gm ----
  for (int i = 0; i < 3; i++) {
    k_bn_part<<<100, 256, 0, stream>>>(S2, 128, 2, ps, ps2);
    k_bn_fin<<<128, 128, 0, stream>>>(ps, ps2, 128, (float)NHIGH, w[18] + i * 128,
                                      w[19] + i * 128, sc, sh);
    k_gemm_lin<128, true, true, false><<<g1, 256, 0, stream>>>(
        S2, sc, sh, w[20] + i * 16384, w[21] + i * 128, S0, NHIGH, 128);
    k_gemm_lin<128, true, true, false><<<g1, 256, 0, stream>>>(
        S2, sc, sh, w[22] + i * 16384, w[23] + i * 128, S1, NHIGH, 128);
    k_gat_hh<2, false><<<NHIGH, 64, 0, stream>>>(S0, S1, w[24] + i * 128,
                                                 w[25] + i * 128, rpH, colH, S2);
  }

  // ---- Stage 5: g5 ----
  k_bn_part<<<100, 256, 0, stream>>>(S2, 128, 2, ps, ps2);
  k_bn_fin<<<128, 128, 0, stream>>>(ps, ps2, 128, (float)NHIGH, w[18] + 384,
                                    w[19] + 384, sc, sh);
  k_gemm_lin<128, true, true, false><<<g2, 256, 0, stream>>>(
      S2, sc, sh, w[26], w[27], S0, NHIGH, 64);
  k_gemm_lin<128, true, true, false><<<g2, 256, 0, stream>>>(
      S2, sc, sh, w[28], w[29], S1, NHIGH, 64);
  k_gat_hh<1, true><<<NHIGH, 64, 0, stream>>>(S0, S1, w[30], w[31], rpH, colH, S2);

  // ---- Stage 6: MLP ----
  k_gemm_lin<64, false, false, true><<<g2, 256, 0, stream>>>(
      S2, sc, sh, w[32], w[33], S0, NHIGH, 64);
  k_linear<64, 32, true><<<nb((long long)NHIGH * 32), 256, 0, stream>>>(
      S0, w[34], w[35], S1, NHIGH);
  k_linear<32, 1, false><<<nb((long long)NHIGH), 256, 0, stream>>>(
      S1, w[36], w[37], (float*)d_out, NHIGH);
}